// Round 3
// baseline (368.553 us; speedup 1.0000x reference)
//
#include <hip/hip_runtime.h>
#include <cstdint>
#include <cstddef>

typedef __bf16 bf16x8 __attribute__((ext_vector_type(8)));
typedef float  f32x4  __attribute__((ext_vector_type(4)));

#define TT 8192
#define EE 1024
#define NCHUNK 128
#define CLEN 64    // TT / NCHUNK
#define LDSK 40    // padded LDS row stride in shorts (80B = 20 banks -> 2-way max, free)

__device__ __forceinline__ unsigned short f2bf(float f) {
    union { float f; unsigned int u; } v; v.f = f;
    unsigned int r = v.u + 0x7FFFu + ((v.u >> 16) & 1u);
    return (unsigned short)(r >> 16);
}
__device__ __forceinline__ float b2f(unsigned int h) {
    union { unsigned int u; float f; } v; v.u = h << 16; return v.f;
}

// ---------------------------------------------------------------------------
// Transpose W (E x E fp32, row-major) -> Wt (N x K bf16, row-major), 4 Ws.
// grid (32,32,4), block (32,8)
// ---------------------------------------------------------------------------
__global__ void wt_kernel(const float* __restrict__ Wk, const float* __restrict__ Wv,
                          const float* __restrict__ Wr, const float* __restrict__ Wo,
                          unsigned short* __restrict__ Tk, unsigned short* __restrict__ Tv,
                          unsigned short* __restrict__ Tr, unsigned short* __restrict__ To) {
    __shared__ float tile[32][33];
    const float* W; unsigned short* D;
    switch (blockIdx.z) {
        case 0:  W = Wk; D = Tk; break;
        case 1:  W = Wv; D = Tv; break;
        case 2:  W = Wr; D = Tr; break;
        default: W = Wo; D = To; break;
    }
    const int bx = blockIdx.x * 32, by = blockIdx.y * 32;
    const int tx = threadIdx.x, ty = threadIdx.y;
#pragma unroll
    for (int r = 0; r < 4; ++r)
        tile[ty + 8 * r][tx] = W[(size_t)(by + ty + 8 * r) * EE + bx + tx];
    __syncthreads();
#pragma unroll
    for (int r = 0; r < 4; ++r)
        D[(size_t)(bx + ty + 8 * r) * EE + by + tx] = f2bf(tile[tx][ty + 8 * r]);
}

// ---------------------------------------------------------------------------
// Fused k/v/r GEMM: blockIdx.z selects {Wk->k, Wv->v, Wr->sigmoid(r)}.
// A built on the fly: mix(x[t], x[t-1]|sx, tm) -> bf16.  C = bf16.
// 128x128 tile, BK=32, 256 threads.  grid (64, 8, 3).
// ---------------------------------------------------------------------------
__global__ __launch_bounds__(256, 4) void gemm_kvr(
        const float* __restrict__ X, const float* __restrict__ SX,
        const float* __restrict__ tmk, const float* __restrict__ tmv,
        const float* __restrict__ tmr,
        const unsigned short* __restrict__ Wkt, const unsigned short* __restrict__ Wvt,
        const unsigned short* __restrict__ Wrt,
        unsigned short* __restrict__ outK, unsigned short* __restrict__ outV,
        unsigned short* __restrict__ outR) {
    __shared__ __align__(16) unsigned short As[128 * LDSK];
    __shared__ __align__(16) unsigned short Bs[128 * LDSK];
    const int z = blockIdx.z;
    const float* TM = (z == 0) ? tmk : (z == 1) ? tmv : tmr;
    const unsigned short* Bt = (z == 0) ? Wkt : (z == 1) ? Wvt : Wrt;
    unsigned short* Cout = (z == 0) ? outK : (z == 1) ? outV : outR;

    const int tid  = threadIdx.x;
    const int wave = tid >> 6, lane = tid & 63;
    const int wm = (wave >> 1) * 64, wn = (wave & 1) * 64;
    const int l15 = lane & 15, lq = lane >> 4;
    const int bm = blockIdx.x * 128, bn = blockIdx.y * 128;

    f32x4 acc[4][4] = {};

    for (int kt = 0; kt < 1024; kt += 32) {
        __syncthreads();
#pragma unroll
        for (int p = 0; p < 2; ++p) {
            const int li  = p * 256 + tid;
            const int row = li >> 2, q = li & 3;
            const int e0  = kt + q * 8;
            {   // A with fused token-shift mix
                const int t = bm + row;
                const float* xr = X + (size_t)t * EE + e0;
                const float* pr = (t > 0) ? (X + (size_t)(t - 1) * EE + e0) : (SX + e0);
                float4 xa = *(const float4*)xr, xb = *(const float4*)(xr + 4);
                float4 pa = *(const float4*)pr, pb = *(const float4*)(pr + 4);
                float4 ma = *(const float4*)(TM + e0), mb = *(const float4*)(TM + e0 + 4);
                ushort4 lo, hi;
                lo.x = f2bf(fmaf(ma.x, xa.x - pa.x, pa.x));
                lo.y = f2bf(fmaf(ma.y, xa.y - pa.y, pa.y));
                lo.z = f2bf(fmaf(ma.z, xa.z - pa.z, pa.z));
                lo.w = f2bf(fmaf(ma.w, xa.w - pa.w, pa.w));
                hi.x = f2bf(fmaf(mb.x, xb.x - pb.x, pb.x));
                hi.y = f2bf(fmaf(mb.y, xb.y - pb.y, pb.y));
                hi.z = f2bf(fmaf(mb.z, xb.z - pb.z, pb.z));
                hi.w = f2bf(fmaf(mb.w, xb.w - pb.w, pb.w));
                *(ushort4*)(&As[row * LDSK + q * 8])     = lo;
                *(ushort4*)(&As[row * LDSK + q * 8 + 4]) = hi;
            }
            *(uint4*)(&Bs[row * LDSK + q * 8]) =
                *(const uint4*)(Bt + (size_t)(bn + row) * 1024 + e0);
        }
        __syncthreads();
        bf16x8 af[4], bfr[4];
#pragma unroll
        for (int i = 0; i < 4; ++i) {
            af[i]  = *(const bf16x8*)(&As[(wm + i * 16 + l15) * LDSK + lq * 8]);
            bfr[i] = *(const bf16x8*)(&Bs[(wn + i * 16 + l15) * LDSK + lq * 8]);
        }
#pragma unroll
        for (int i = 0; i < 4; ++i)
#pragma unroll
            for (int j = 0; j < 4; ++j)
                acc[i][j] = __builtin_amdgcn_mfma_f32_16x16x32_bf16(af[i], bfr[j], acc[i][j], 0, 0, 0);
    }

    const bool sig = (z == 2);
#pragma unroll
    for (int i = 0; i < 4; ++i)
#pragma unroll
        for (int j = 0; j < 4; ++j) {
            const int col = bn + wn + j * 16 + l15;
#pragma unroll
            for (int r = 0; r < 4; ++r) {
                const int row = bm + wm + i * 16 + lq * 4 + r;
                float val = acc[i][j][r];
                if (sig) val = 1.f / (1.f + __expf(-val));
                Cout[(size_t)row * 1024 + col] = f2bf(val);
            }
        }
}

// ---------------------------------------------------------------------------
// Wo GEMM:  C[M,N] f32 = A[M,K] bf16 @ Bt[N,K]^T + Res.
// 128x64 tile (more blocks in flight), BK=32, 256 threads.  grid (64, 16).
// ---------------------------------------------------------------------------
__global__ __launch_bounds__(256, 4) void gemm_wo(const unsigned short* __restrict__ A,
                                                  const unsigned short* __restrict__ Bt,
                                                  const float* __restrict__ Res,
                                                  float* __restrict__ C) {
    __shared__ __align__(16) unsigned short As[128 * LDSK];
    __shared__ __align__(16) unsigned short Bs[64 * LDSK];
    const int tid  = threadIdx.x;
    const int wave = tid >> 6, lane = tid & 63;
    const int wm = (wave >> 1) * 64, wn = (wave & 1) * 32;
    const int l15 = lane & 15, lq = lane >> 4;
    const int bm = blockIdx.x * 128, bn = blockIdx.y * 64;

    f32x4 acc[4][2] = {};

    for (int kt = 0; kt < 1024; kt += 32) {
        __syncthreads();
#pragma unroll
        for (int p = 0; p < 2; ++p) {
            const int li  = p * 256 + tid;
            const int row = li >> 2, q = li & 3;
            *(uint4*)(&As[row * LDSK + q * 8]) =
                *(const uint4*)(A + (size_t)(bm + row) * 1024 + kt + q * 8);
        }
        {
            const int row = tid >> 2, q = tid & 3;
            *(uint4*)(&Bs[row * LDSK + q * 8]) =
                *(const uint4*)(Bt + (size_t)(bn + row) * 1024 + kt + q * 8);
        }
        __syncthreads();
        bf16x8 af[4], bfr[2];
#pragma unroll
        for (int i = 0; i < 4; ++i)
            af[i] = *(const bf16x8*)(&As[(wm + i * 16 + l15) * LDSK + lq * 8]);
#pragma unroll
        for (int j = 0; j < 2; ++j)
            bfr[j] = *(const bf16x8*)(&Bs[(wn + j * 16 + l15) * LDSK + lq * 8]);
#pragma unroll
        for (int i = 0; i < 4; ++i)
#pragma unroll
            for (int j = 0; j < 2; ++j)
                acc[i][j] = __builtin_amdgcn_mfma_f32_16x16x32_bf16(af[i], bfr[j], acc[i][j], 0, 0, 0);
    }

#pragma unroll
    for (int i = 0; i < 4; ++i)
#pragma unroll
        for (int j = 0; j < 2; ++j) {
            const int col = bn + wn + j * 16 + l15;
#pragma unroll
            for (int r = 0; r < 4; ++r) {
                const int row = bm + wm + i * 16 + lq * 4 + r;
                const size_t idx = (size_t)row * 1024 + col;
                C[idx] = acc[i][j][r] + Res[idx];
            }
        }
}

// ---------------------------------------------------------------------------
// WKV pass A: per (chunk, channel) stabilized local summary; 2 channels/thread.
//   S = sum_i exp(w*(L-1-i)+k_i) * (v_i, 1), kept as (sa,sb,sp): S = s*e^sp
// grid NCHUNK*EE/2/256 x 256
// ---------------------------------------------------------------------------
__global__ void wkv_pass_a(const unsigned short* __restrict__ k,
                           const unsigned short* __restrict__ v,
                           const float* __restrict__ td,
                           float* __restrict__ Sa, float* __restrict__ Sb, float* __restrict__ Sp) {
    const int tid = blockIdx.x * 256 + threadIdx.x;
    const int c = tid >> 9, e = (tid & 511) * 2;
    const float w0 = -__expf(td[e]), w1 = -__expf(td[e + 1]);
    float sa0 = 0.f, sb0 = 0.f, sp0 = -1e30f;
    float sa1 = 0.f, sb1 = 0.f, sp1 = -1e30f;
    const size_t base = (size_t)c * CLEN * EE + e;
    for (int i = 0; i < CLEN; ++i) {
        const size_t idx = base + (size_t)i * EE;
        const unsigned int ku = *(const unsigned int*)(k + idx);
        const unsigned int vu = *(const unsigned int*)(v + idx);
        const float rem = (float)(CLEN - 1 - i);
        {
            const float kk = b2f(ku & 0xffffu), vv = b2f(vu & 0xffffu);
            const float q  = fmaf(w0, rem, kk);
            const float p2 = fmaxf(sp0, q);
            const float e1 = __expf(sp0 - p2), e2 = __expf(q - p2);
            sa0 = fmaf(e1, sa0, e2 * vv); sb0 = fmaf(e1, sb0, e2); sp0 = p2;
        }
        {
            const float kk = b2f(ku >> 16), vv = b2f(vu >> 16);
            const float q  = fmaf(w1, rem, kk);
            const float p2 = fmaxf(sp1, q);
            const float e1 = __expf(sp1 - p2), e2 = __expf(q - p2);
            sa1 = fmaf(e1, sa1, e2 * vv); sb1 = fmaf(e1, sb1, e2); sp1 = p2;
        }
    }
    const int o = c * EE + e;
    *(float2*)(Sa + o) = make_float2(sa0, sa1);
    *(float2*)(Sb + o) = make_float2(sb0, sb1);
    *(float2*)(Sp + o) = make_float2(sp0, sp1);
}

// ---------------------------------------------------------------------------
// WKV pass B: sequential exclusive scan over chunk summaries (per channel);
// also writes x[-1] and final (aa,bb,pp) to the output tail.  grid 4 x 256
// ---------------------------------------------------------------------------
__global__ void wkv_pass_b(const float* __restrict__ aa, const float* __restrict__ bb,
                           const float* __restrict__ pp, const float* __restrict__ td,
                           const float* __restrict__ x,
                           const float* __restrict__ Sa, const float* __restrict__ Sb,
                           const float* __restrict__ Sp,
                           float* __restrict__ ina, float* __restrict__ inb,
                           float* __restrict__ inp, float* __restrict__ outTail) {
    const int e = blockIdx.x * 256 + threadIdx.x;   // 0..1023
    const float w  = -__expf(td[e]);
    const float wL = w * (float)CLEN;
    float a = aa[e], b = bb[e], p = pp[e];
    for (int c = 0; c < NCHUNK; ++c) {
        const int idx = c * EE + e;
        ina[idx] = a; inb[idx] = b; inp[idx] = p;
        const float sa = Sa[idx], sb = Sb[idx], sp = Sp[idx];
        const float pw = p + wL;
        const float p2 = fmaxf(pw, sp);
        const float e1 = __expf(pw - p2), e2 = __expf(sp - p2);
        a = fmaf(e1, a, e2 * sa);
        b = fmaf(e1, b, e2 * sb);
        p = p2;
    }
    outTail[e]          = x[(size_t)(TT - 1) * EE + e];   // x[-1]
    outTail[EE + e]     = a;                              // aa_f
    outTail[2 * EE + e] = b;                              // bb_f
    outTail[3 * EE + e] = p;                              // pp_f
}

// ---------------------------------------------------------------------------
// WKV pass C: replay each chunk from its incoming state; ry holds sigmoid(r)
// on input, overwritten in place with y = sigmoid(r)*wkv (bf16). 2 ch/thread.
// grid NCHUNK*EE/2/256 x 256
// ---------------------------------------------------------------------------
__global__ void wkv_pass_c(const unsigned short* __restrict__ k,
                           const unsigned short* __restrict__ v,
                           const float* __restrict__ tf, const float* __restrict__ td,
                           const float* __restrict__ ina, const float* __restrict__ inb,
                           const float* __restrict__ inp,
                           unsigned short* ry) {
    const int tid = blockIdx.x * 256 + threadIdx.x;
    const int c = tid >> 9, e = (tid & 511) * 2;
    const float w0 = -__expf(td[e]), w1 = -__expf(td[e + 1]);
    const float u0 = tf[e], u1 = tf[e + 1];
    const int o = c * EE + e;
    float a0 = ina[o], b0 = inb[o], p0 = inp[o];
    float a1 = ina[o + 1], b1 = inb[o + 1], p1 = inp[o + 1];
    const size_t base = (size_t)c * CLEN * EE + e;
    for (int i = 0; i < CLEN; ++i) {
        const size_t idx = base + (size_t)i * EE;
        const unsigned int ku = *(const unsigned int*)(k + idx);
        const unsigned int vu = *(const unsigned int*)(v + idx);
        const unsigned int ru = *(const unsigned int*)(ry + idx);
        float y0, y1;
        {
            const float kk = b2f(ku & 0xffffu), vv = b2f(vu & 0xffffu), rr = b2f(ru & 0xffffu);
            const float ww = u0 + kk;
            const float pq = fmaxf(p0, ww);
            const float e1 = __expf(p0 - pq), e2 = __expf(ww - pq);
            y0 = rr * (fmaf(e1, a0, e2 * vv) / fmaf(e1, b0, e2));
            const float ww2 = w0 + p0;
            const float p2  = fmaxf(ww2, kk);
            const float e1b = __expf(ww2 - p2), e2b = __expf(kk - p2);
            a0 = fmaf(e1b, a0, e2b * vv); b0 = fmaf(e1b, b0, e2b); p0 = p2;
        }
        {
            const float kk = b2f(ku >> 16), vv = b2f(vu >> 16), rr = b2f(ru >> 16);
            const float ww = u1 + kk;
            const float pq = fmaxf(p1, ww);
            const float e1 = __expf(p1 - pq), e2 = __expf(ww - pq);
            y1 = rr * (fmaf(e1, a1, e2 * vv) / fmaf(e1, b1, e2));
            const float ww2 = w1 + p1;
            const float p2  = fmaxf(ww2, kk);
            const float e1b = __expf(ww2 - p2), e2b = __expf(kk - p2);
            a1 = fmaf(e1b, a1, e2b * vv); b1 = fmaf(e1b, b1, e2b); p1 = p2;
        }
        *(unsigned int*)(ry + idx) = (unsigned int)f2bf(y0) | ((unsigned int)f2bf(y1) << 16);
    }
}

// ---------------------------------------------------------------------------
extern "C" void kernel_launch(void* const* d_in, const int* in_sizes, int n_in,
                              void* d_out, int out_size, void* d_ws, size_t ws_size,
                              hipStream_t stream) {
    const float* x   = (const float*)d_in[0];
    const float* sx  = (const float*)d_in[1];
    const float* aa  = (const float*)d_in[2];
    const float* bb  = (const float*)d_in[3];
    const float* pp  = (const float*)d_in[4];
    const float* tf  = (const float*)d_in[5];
    const float* td  = (const float*)d_in[6];
    const float* tmk = (const float*)d_in[7];
    const float* tmv = (const float*)d_in[8];
    const float* tmr = (const float*)d_in[9];
    const float* Wk  = (const float*)d_in[10];
    const float* Wv  = (const float*)d_in[11];
    const float* Wr  = (const float*)d_in[12];
    const float* Wo  = (const float*)d_in[13];
    float* out = (float*)d_out;

    // --- workspace layout: 27 MB total ---
    char* ws = (char*)d_ws;
    const size_t MB = 1ull << 20;
    unsigned short* Wkt = (unsigned short*)(ws + 0 * MB);   // 2 MB each
    unsigned short* Wvt = (unsigned short*)(ws + 2 * MB);
    unsigned short* Wrt = (unsigned short*)(ws + 4 * MB);
    unsigned short* Wot = (unsigned short*)(ws + 6 * MB);
    unsigned short* ry  = (unsigned short*)(ws + 8 * MB);   // 16 MB: sigmoid(r), then y
    const size_t QK = (size_t)NCHUNK * EE * sizeof(float);  // 512 KB
    float* Sa  = (float*)(ws + 24 * MB);
    float* Sb  = (float*)(ws + 24 * MB + QK);
    float* Sp  = (float*)(ws + 24 * MB + 2 * QK);
    float* ina = (float*)(ws + 24 * MB + 3 * QK);
    float* inb = (float*)(ws + 24 * MB + 4 * QK);
    float* inp = (float*)(ws + 24 * MB + 5 * QK);

    // --- d_out doubles as scratch for bf16 k and v until the final GEMM ---
    unsigned short* kf = (unsigned short*)d_out;                        // 16 MB
    unsigned short* vf = (unsigned short*)d_out + (size_t)TT * EE;      // 16 MB

    // 1. W transposes -> bf16
    wt_kernel<<<dim3(32, 32, 4), dim3(32, 8), 0, stream>>>(Wk, Wv, Wr, Wo, Wkt, Wvt, Wrt, Wot);
    // 2. fused k / v / sigmoid(r) GEMMs (one dispatch, 1536 blocks)
    gemm_kvr<<<dim3(64, 8, 3), 256, 0, stream>>>(x, sx, tmk, tmv, tmr,
                                                 Wkt, Wvt, Wrt, kf, vf, ry);
    // 3-5. chunked WKV scan
    wkv_pass_a<<<(NCHUNK * EE / 2) / 256, 256, 0, stream>>>(kf, vf, td, Sa, Sb, Sp);
    wkv_pass_b<<<4, 256, 0, stream>>>(aa, bb, pp, td, x, Sa, Sb, Sp, ina, inb, inp,
                                      out + (size_t)TT * EE);
    wkv_pass_c<<<(NCHUNK * EE / 2) / 256, 256, 0, stream>>>(kf, vf, tf, td, ina, inb, inp, ry);
    // 6. out = x + y @ Wo   (overwrites the k/v scratch in d_out)
    gemm_wo<<<dim3(64, 16), 256, 0, stream>>>(ry, Wot, x, out);
}

// Round 4
// 287.768 us; speedup vs baseline: 1.2807x; 1.2807x over previous
//
#include <hip/hip_runtime.h>
#include <cstdint>
#include <cstddef>

typedef __bf16 bf16x8 __attribute__((ext_vector_type(8)));
typedef float  f32x4  __attribute__((ext_vector_type(4)));

#define TT 8192
#define EE 1024
#define NCHUNK 128
#define CLEN 64    // TT / NCHUNK
#define LDSK 40    // fallback-path padded LDS stride (shorts)

__device__ __forceinline__ unsigned short f2bf(float f) {
    union { float f; unsigned int u; } v; v.f = f;
    unsigned int r = v.u + 0x7FFFu + ((v.u >> 16) & 1u);
    return (unsigned short)(r >> 16);
}
__device__ __forceinline__ float b2f(unsigned int h) {
    union { unsigned int u; float f; } v; v.u = h << 16; return v.f;
}
__device__ __forceinline__ void gload_lds16(const void* g, void* l) {
    __builtin_amdgcn_global_load_lds((__attribute__((address_space(1))) void*)g,
                                     (__attribute__((address_space(3))) void*)l, 16, 0, 0);
}

// ---------------------------------------------------------------------------
// Transpose W (E x E fp32, row-major) -> Wt (N x K bf16, row-major), 4 Ws.
// grid (32,32,4), block (32,8)
// ---------------------------------------------------------------------------
__global__ void wt_kernel(const float* __restrict__ Wk, const float* __restrict__ Wv,
                          const float* __restrict__ Wr, const float* __restrict__ Wo,
                          unsigned short* __restrict__ Tk, unsigned short* __restrict__ Tv,
                          unsigned short* __restrict__ Tr, unsigned short* __restrict__ To) {
    __shared__ float tile[32][33];
    const float* W; unsigned short* D;
    switch (blockIdx.z) {
        case 0:  W = Wk; D = Tk; break;
        case 1:  W = Wv; D = Tv; break;
        case 2:  W = Wr; D = Tr; break;
        default: W = Wo; D = To; break;
    }
    const int bx = blockIdx.x * 32, by = blockIdx.y * 32;
    const int tx = threadIdx.x, ty = threadIdx.y;
#pragma unroll
    for (int r = 0; r < 4; ++r)
        tile[ty + 8 * r][tx] = W[(size_t)(by + ty + 8 * r) * EE + bx + tx];
    __syncthreads();
#pragma unroll
    for (int r = 0; r < 4; ++r)
        D[(size_t)(bx + ty + 8 * r) * EE + by + tx] = f2bf(tile[tx][ty + 8 * r]);
}

// ---------------------------------------------------------------------------
// Token-shift mixing: kx/vx/rx bf16.  thread = 4 consecutive elements.
// grid TT*EE/4/256, 256 threads
// ---------------------------------------------------------------------------
__global__ void mix3_kernel(const float* __restrict__ x, const float* __restrict__ sx,
                            const float* __restrict__ tmk, const float* __restrict__ tmv,
                            const float* __restrict__ tmr,
                            unsigned short* __restrict__ kxb, unsigned short* __restrict__ vxb,
                            unsigned short* __restrict__ rxb) {
    const int gid  = blockIdx.x * blockDim.x + threadIdx.x;
    const int base = gid * 4;
    const int t = base >> 10;
    const int e = base & (EE - 1);
    float4 xv = *(const float4*)(x + base);
    float4 pv = (t > 0) ? *(const float4*)(x + base - EE) : *(const float4*)(sx + e);
    float4 mk = *(const float4*)(tmk + e);
    float4 mv = *(const float4*)(tmv + e);
    float4 mr = *(const float4*)(tmr + e);
    ushort4 ko, vo, ro;
    ko.x = f2bf(fmaf(mk.x, xv.x - pv.x, pv.x));
    ko.y = f2bf(fmaf(mk.y, xv.y - pv.y, pv.y));
    ko.z = f2bf(fmaf(mk.z, xv.z - pv.z, pv.z));
    ko.w = f2bf(fmaf(mk.w, xv.w - pv.w, pv.w));
    vo.x = f2bf(fmaf(mv.x, xv.x - pv.x, pv.x));
    vo.y = f2bf(fmaf(mv.y, xv.y - pv.y, pv.y));
    vo.z = f2bf(fmaf(mv.z, xv.z - pv.z, pv.z));
    vo.w = f2bf(fmaf(mv.w, xv.w - pv.w, pv.w));
    ro.x = f2bf(fmaf(mr.x, xv.x - pv.x, pv.x));
    ro.y = f2bf(fmaf(mr.y, xv.y - pv.y, pv.y));
    ro.z = f2bf(fmaf(mr.z, xv.z - pv.z, pv.z));
    ro.w = f2bf(fmaf(mr.w, xv.w - pv.w, pv.w));
    *(ushort4*)(kxb + base) = ko;
    *(ushort4*)(vxb + base) = vo;
    *(ushort4*)(rxb + base) = ro;
}

// ---------------------------------------------------------------------------
// m97-structure GEMM: C bf16 [M,N] = A bf16 [M,K] @ Bt bf16 [N,K]^T,
// optional sigmoid.  global_load_lds dwordx4 staging, unpadded 32-short rows.
// 128x128 tile, BK=32, 256 threads.  grid (64,8,z) — z picks operand set.
// ---------------------------------------------------------------------------
__global__ __launch_bounds__(256) void gemm_bf(
        const unsigned short* __restrict__ A0, const unsigned short* __restrict__ B0,
        unsigned short* __restrict__ C0, const int sig0,
        const unsigned short* __restrict__ A1, const unsigned short* __restrict__ B1,
        unsigned short* __restrict__ C1, const int sig1) {
    __shared__ __align__(16) unsigned short As[128 * 32];
    __shared__ __align__(16) unsigned short Bs[128 * 32];
    const int z = blockIdx.z;
    const unsigned short* A  = z ? A1 : A0;
    const unsigned short* Bt = z ? B1 : B0;
    unsigned short* C        = z ? C1 : C0;
    const int sig            = z ? sig1 : sig0;

    const int tid  = threadIdx.x;
    const int wave = tid >> 6, lane = tid & 63;
    const int wm = (wave >> 1) * 64, wn = (wave & 1) * 64;
    const int l15 = lane & 15, lq = lane >> 4;
    const int lrow = lane >> 2, lcol = (lane & 3) * 8;   // staging: 4 lanes/row
    const int bm = blockIdx.x * 128, bn = blockIdx.y * 128;

    f32x4 acc[4][4] = {};

    for (int kt = 0; kt < 1024; kt += 32) {
        __syncthreads();
#pragma unroll
        for (int p = 0; p < 2; ++p) {
            const int r0 = p * 64 + wave * 16;      // 16 rows per wave-instr
            gload_lds16(A  + (size_t)(bm + r0 + lrow) * 1024 + kt + lcol, &As[r0 * 32]);
            gload_lds16(Bt + (size_t)(bn + r0 + lrow) * 1024 + kt + lcol, &Bs[r0 * 32]);
        }
        __syncthreads();
        bf16x8 af[4], bfr[4];
#pragma unroll
        for (int i = 0; i < 4; ++i) {
            af[i]  = *(const bf16x8*)(&As[(wm + i * 16 + l15) * 32 + lq * 8]);
            bfr[i] = *(const bf16x8*)(&Bs[(wn + i * 16 + l15) * 32 + lq * 8]);
        }
#pragma unroll
        for (int i = 0; i < 4; ++i)
#pragma unroll
            for (int j = 0; j < 4; ++j)
                acc[i][j] = __builtin_amdgcn_mfma_f32_16x16x32_bf16(af[i], bfr[j], acc[i][j], 0, 0, 0);
    }

#pragma unroll
    for (int i = 0; i < 4; ++i)
#pragma unroll
        for (int j = 0; j < 4; ++j) {
            const int col = bn + wn + j * 16 + l15;
#pragma unroll
            for (int r = 0; r < 4; ++r) {
                const int row = bm + wm + i * 16 + lq * 4 + r;
                float val = acc[i][j][r];
                if (sig) val = 1.f / (1.f + __expf(-val));
                C[(size_t)row * 1024 + col] = f2bf(val);
            }
        }
}

// ---------------------------------------------------------------------------
// m97-structure Wo GEMM: C f32 = A bf16 @ Bt^T + Res.  grid (64,8).
// ---------------------------------------------------------------------------
__global__ __launch_bounds__(256) void gemm_wo(const unsigned short* __restrict__ A,
                                               const unsigned short* __restrict__ Bt,
                                               const float* __restrict__ Res,
                                               float* __restrict__ C) {
    __shared__ __align__(16) unsigned short As[128 * 32];
    __shared__ __align__(16) unsigned short Bs[128 * 32];
    const int tid  = threadIdx.x;
    const int wave = tid >> 6, lane = tid & 63;
    const int wm = (wave >> 1) * 64, wn = (wave & 1) * 64;
    const int l15 = lane & 15, lq = lane >> 4;
    const int lrow = lane >> 2, lcol = (lane & 3) * 8;
    const int bm = blockIdx.x * 128, bn = blockIdx.y * 128;

    f32x4 acc[4][4] = {};

    for (int kt = 0; kt < 1024; kt += 32) {
        __syncthreads();
#pragma unroll
        for (int p = 0; p < 2; ++p) {
            const int r0 = p * 64 + wave * 16;
            gload_lds16(A  + (size_t)(bm + r0 + lrow) * 1024 + kt + lcol, &As[r0 * 32]);
            gload_lds16(Bt + (size_t)(bn + r0 + lrow) * 1024 + kt + lcol, &Bs[r0 * 32]);
        }
        __syncthreads();
        bf16x8 af[4], bfr[4];
#pragma unroll
        for (int i = 0; i < 4; ++i) {
            af[i]  = *(const bf16x8*)(&As[(wm + i * 16 + l15) * 32 + lq * 8]);
            bfr[i] = *(const bf16x8*)(&Bs[(wn + i * 16 + l15) * 32 + lq * 8]);
        }
#pragma unroll
        for (int i = 0; i < 4; ++i)
#pragma unroll
            for (int j = 0; j < 4; ++j)
                acc[i][j] = __builtin_amdgcn_mfma_f32_16x16x32_bf16(af[i], bfr[j], acc[i][j], 0, 0, 0);
    }

#pragma unroll
    for (int i = 0; i < 4; ++i)
#pragma unroll
        for (int j = 0; j < 4; ++j) {
            const int col = bn + wn + j * 16 + l15;
#pragma unroll
            for (int r = 0; r < 4; ++r) {
                const int row = bm + wm + i * 16 + lq * 4 + r;
                const size_t idx = (size_t)row * 1024 + col;
                C[idx] = acc[i][j][r] + Res[idx];
            }
        }
}

// ---------------------------------------------------------------------------
// FALLBACK (small ws): fused-mix k/v/r GEMM, round-3 structure.
// ---------------------------------------------------------------------------
__global__ __launch_bounds__(256, 4) void gemm_kvr(
        const float* __restrict__ X, const float* __restrict__ SX,
        const float* __restrict__ tmk, const float* __restrict__ tmv,
        const float* __restrict__ tmr,
        const unsigned short* __restrict__ Wkt, const unsigned short* __restrict__ Wvt,
        const unsigned short* __restrict__ Wrt,
        unsigned short* __restrict__ outK, unsigned short* __restrict__ outV,
        unsigned short* __restrict__ outR) {
    __shared__ __align__(16) unsigned short As[128 * LDSK];
    __shared__ __align__(16) unsigned short Bs[128 * LDSK];
    const int z = blockIdx.z;
    const float* TM = (z == 0) ? tmk : (z == 1) ? tmv : tmr;
    const unsigned short* Bt = (z == 0) ? Wkt : (z == 1) ? Wvt : Wrt;
    unsigned short* Cout = (z == 0) ? outK : (z == 1) ? outV : outR;

    const int tid  = threadIdx.x;
    const int wave = tid >> 6, lane = tid & 63;
    const int wm = (wave >> 1) * 64, wn = (wave & 1) * 64;
    const int l15 = lane & 15, lq = lane >> 4;
    const int bm = blockIdx.x * 128, bn = blockIdx.y * 128;

    f32x4 acc[4][4] = {};

    for (int kt = 0; kt < 1024; kt += 32) {
        __syncthreads();
#pragma unroll
        for (int p = 0; p < 2; ++p) {
            const int li  = p * 256 + tid;
            const int row = li >> 2, q = li & 3;
            const int e0  = kt + q * 8;
            {
                const int t = bm + row;
                const float* xr = X + (size_t)t * EE + e0;
                const float* pr = (t > 0) ? (X + (size_t)(t - 1) * EE + e0) : (SX + e0);
                float4 xa = *(const float4*)xr, xb = *(const float4*)(xr + 4);
                float4 pa = *(const float4*)pr, pb = *(const float4*)(pr + 4);
                float4 ma = *(const float4*)(TM + e0), mb = *(const float4*)(TM + e0 + 4);
                ushort4 lo, hi;
                lo.x = f2bf(fmaf(ma.x, xa.x - pa.x, pa.x));
                lo.y = f2bf(fmaf(ma.y, xa.y - pa.y, pa.y));
                lo.z = f2bf(fmaf(ma.z, xa.z - pa.z, pa.z));
                lo.w = f2bf(fmaf(ma.w, xa.w - pa.w, pa.w));
                hi.x = f2bf(fmaf(mb.x, xb.x - pb.x, pb.x));
                hi.y = f2bf(fmaf(mb.y, xb.y - pb.y, pb.y));
                hi.z = f2bf(fmaf(mb.z, xb.z - pb.z, pb.z));
                hi.w = f2bf(fmaf(mb.w, xb.w - pb.w, pb.w));
                *(ushort4*)(&As[row * LDSK + q * 8])     = lo;
                *(ushort4*)(&As[row * LDSK + q * 8 + 4]) = hi;
            }
            *(uint4*)(&Bs[row * LDSK + q * 8]) =
                *(const uint4*)(Bt + (size_t)(bn + row) * 1024 + e0);
        }
        __syncthreads();
        bf16x8 af[4], bfr[4];
#pragma unroll
        for (int i = 0; i < 4; ++i) {
            af[i]  = *(const bf16x8*)(&As[(wm + i * 16 + l15) * LDSK + lq * 8]);
            bfr[i] = *(const bf16x8*)(&Bs[(wn + i * 16 + l15) * LDSK + lq * 8]);
        }
#pragma unroll
        for (int i = 0; i < 4; ++i)
#pragma unroll
            for (int j = 0; j < 4; ++j)
                acc[i][j] = __builtin_amdgcn_mfma_f32_16x16x32_bf16(af[i], bfr[j], acc[i][j], 0, 0, 0);
    }

    const bool sig = (z == 2);
#pragma unroll
    for (int i = 0; i < 4; ++i)
#pragma unroll
        for (int j = 0; j < 4; ++j) {
            const int col = bn + wn + j * 16 + l15;
#pragma unroll
            for (int r = 0; r < 4; ++r) {
                const int row = bm + wm + i * 16 + lq * 4 + r;
                float val = acc[i][j][r];
                if (sig) val = 1.f / (1.f + __expf(-val));
                Cout[(size_t)row * 1024 + col] = f2bf(val);
            }
        }
}

// ---------------------------------------------------------------------------
// WKV pass A: per (chunk, channel) stabilized local summary.  grid 512 x 256
// ---------------------------------------------------------------------------
__global__ void wkv_pass_a(const unsigned short* __restrict__ k,
                           const unsigned short* __restrict__ v,
                           const float* __restrict__ td,
                           float* __restrict__ Sa, float* __restrict__ Sb, float* __restrict__ Sp) {
    const int gid = blockIdx.x * 256 + threadIdx.x;
    const int c = gid >> 10, e = gid & (EE - 1);
    const float w = -__expf(td[e]);
    float sa = 0.f, sb = 0.f, sp = -1e30f;
    const size_t base = (size_t)c * CLEN * EE + e;
    for (int i = 0; i < CLEN; ++i) {
        const size_t idx = base + (size_t)i * EE;
        const float kk = b2f(k[idx]), vv = b2f(v[idx]);
        const float q  = fmaf(w, (float)(CLEN - 1 - i), kk);
        const float p2 = fmaxf(sp, q);
        const float e1 = __expf(sp - p2), e2 = __expf(q - p2);
        sa = fmaf(e1, sa, e2 * vv);
        sb = fmaf(e1, sb, e2);
        sp = p2;
    }
    Sa[gid] = sa; Sb[gid] = sb; Sp[gid] = sp;
}

// ---------------------------------------------------------------------------
// WKV pass B: sequential chunk-scan per channel + final-state outputs.
// grid 4 x 256
// ---------------------------------------------------------------------------
__global__ void wkv_pass_b(const float* __restrict__ aa, const float* __restrict__ bb,
                           const float* __restrict__ pp, const float* __restrict__ td,
                           const float* __restrict__ x,
                           const float* __restrict__ Sa, const float* __restrict__ Sb,
                           const float* __restrict__ Sp,
                           float* __restrict__ ina, float* __restrict__ inb,
                           float* __restrict__ inp, float* __restrict__ outTail) {
    const int e = blockIdx.x * 256 + threadIdx.x;
    const float w  = -__expf(td[e]);
    const float wL = w * (float)CLEN;
    float a = aa[e], b = bb[e], p = pp[e];
    for (int c = 0; c < NCHUNK; ++c) {
        const int idx = c * EE + e;
        ina[idx] = a; inb[idx] = b; inp[idx] = p;
        const float sa = Sa[idx], sb = Sb[idx], sp = Sp[idx];
        const float pw = p + wL;
        const float p2 = fmaxf(pw, sp);
        const float e1 = __expf(pw - p2), e2 = __expf(sp - p2);
        a = fmaf(e1, a, e2 * sa);
        b = fmaf(e1, b, e2 * sb);
        p = p2;
    }
    outTail[e]          = x[(size_t)(TT - 1) * EE + e];
    outTail[EE + e]     = a;
    outTail[2 * EE + e] = b;
    outTail[3 * EE + e] = p;
}

// ---------------------------------------------------------------------------
// WKV pass C: replay chunks; ry = sigmoid(r) in, y = sigmoid(r)*wkv out.
// grid 512 x 256
// ---------------------------------------------------------------------------
__global__ void wkv_pass_c(const unsigned short* __restrict__ k,
                           const unsigned short* __restrict__ v,
                           const float* __restrict__ tf, const float* __restrict__ td,
                           const float* __restrict__ ina, const float* __restrict__ inb,
                           const float* __restrict__ inp,
                           unsigned short* ry) {
    const int gid = blockIdx.x * 256 + threadIdx.x;
    const int c = gid >> 10, e = gid & (EE - 1);
    const float w = -__expf(td[e]);
    const float u = tf[e];
    float a = ina[gid], b = inb[gid], p = inp[gid];
    const size_t base = (size_t)c * CLEN * EE + e;
    for (int i = 0; i < CLEN; ++i) {
        const size_t idx = base + (size_t)i * EE;
        const float kk = b2f(k[idx]), vv = b2f(v[idx]);
        const float rr = b2f(ry[idx]);
        const float ww = u + kk;
        const float pq = fmaxf(p, ww);
        const float e1 = __expf(p - pq), e2 = __expf(ww - pq);
        const float wkv = fmaf(e1, a, e2 * vv) / fmaf(e1, b, e2);
        ry[idx] = f2bf(rr * wkv);
        const float ww2 = w + p;
        const float p2  = fmaxf(ww2, kk);
        const float e1b = __expf(ww2 - p2), e2b = __expf(kk - p2);
        a = fmaf(e1b, a, e2b * vv);
        b = fmaf(e1b, b, e2b);
        p = p2;
    }
}

// ---------------------------------------------------------------------------
extern "C" void kernel_launch(void* const* d_in, const int* in_sizes, int n_in,
                              void* d_out, int out_size, void* d_ws, size_t ws_size,
                              hipStream_t stream) {
    const float* x   = (const float*)d_in[0];
    const float* sx  = (const float*)d_in[1];
    const float* aa  = (const float*)d_in[2];
    const float* bb  = (const float*)d_in[3];
    const float* pp  = (const float*)d_in[4];
    const float* tf  = (const float*)d_in[5];
    const float* td  = (const float*)d_in[6];
    const float* tmk = (const float*)d_in[7];
    const float* tmv = (const float*)d_in[8];
    const float* tmr = (const float*)d_in[9];
    const float* Wk  = (const float*)d_in[10];
    const float* Wv  = (const float*)d_in[11];
    const float* Wr  = (const float*)d_in[12];
    const float* Wo  = (const float*)d_in[13];
    float* out = (float*)d_out;

    char* ws = (char*)d_ws;
    const size_t MB = 1ull << 20;
    const size_t QK = (size_t)NCHUNK * EE * sizeof(float);  // 512 KB

    unsigned short* Wkt = (unsigned short*)(ws + 0 * MB);   // 2 MB each
    unsigned short* Wvt = (unsigned short*)(ws + 2 * MB);
    unsigned short* Wrt = (unsigned short*)(ws + 4 * MB);
    unsigned short* Wot = (unsigned short*)(ws + 6 * MB);

    const bool big = (ws_size >= 59 * MB);

    // 1. W transposes -> bf16 (both paths)
    wt_kernel<<<dim3(32, 32, 4), dim3(32, 8), 0, stream>>>(Wk, Wv, Wr, Wo, Wkt, Wvt, Wrt, Wot);

    if (big) {
        // ws: [0:8] Wt | [8:24] rxb | [24:40] kf | [40:56] ry | [56:59] scan
        unsigned short* rxb = (unsigned short*)(ws + 8 * MB);
        unsigned short* kf  = (unsigned short*)(ws + 24 * MB);
        unsigned short* ry  = (unsigned short*)(ws + 40 * MB);
        char* scan = ws + 56 * MB;
        float* Sa  = (float*)(scan);
        float* Sb  = (float*)(scan + QK);
        float* Sp  = (float*)(scan + 2 * QK);
        float* ina = (float*)(scan + 3 * QK);
        float* inb = (float*)(scan + 4 * QK);
        float* inp = (float*)(scan + 5 * QK);
        // d_out scratch: kxb [0:16MB], vxb [16:32MB]; vf later overlays kxb.
        unsigned short* kxb = (unsigned short*)d_out;
        unsigned short* vxb = (unsigned short*)d_out + (size_t)TT * EE;
        unsigned short* vf  = kxb;

        mix3_kernel<<<(TT * EE / 4) / 256, 256, 0, stream>>>(x, sx, tmk, tmv, tmr, kxb, vxb, rxb);
        // k and r GEMMs fused in z (1024 blocks); both read d_out/ws, write ws.
        gemm_bf<<<dim3(64, 8, 2), 256, 0, stream>>>(kxb, Wkt, kf, 0, rxb, Wrt, ry, 1);
        // v GEMM: writes vf over kxb (consumed above; stream-ordered).
        gemm_bf<<<dim3(64, 8, 1), 256, 0, stream>>>(vxb, Wvt, vf, 0, nullptr, nullptr, nullptr, 0);
        wkv_pass_a<<<(NCHUNK * EE) / 256, 256, 0, stream>>>(kf, vf, td, Sa, Sb, Sp);
        wkv_pass_b<<<4, 256, 0, stream>>>(aa, bb, pp, td, x, Sa, Sb, Sp, ina, inb, inp,
                                          out + (size_t)TT * EE);
        wkv_pass_c<<<(NCHUNK * EE) / 256, 256, 0, stream>>>(kf, vf, tf, td, ina, inb, inp, ry);
        gemm_wo<<<dim3(64, 8), 256, 0, stream>>>(ry, Wot, x, out);
    } else {
        // ws: [0:8] Wt | [8:24] ry | [24:27] scan   (27 MB, proven)
        unsigned short* ry = (unsigned short*)(ws + 8 * MB);
        char* scan = ws + 24 * MB;
        float* Sa  = (float*)(scan);
        float* Sb  = (float*)(scan + QK);
        float* Sp  = (float*)(scan + 2 * QK);
        float* ina = (float*)(scan + 3 * QK);
        float* inb = (float*)(scan + 4 * QK);
        float* inp = (float*)(scan + 5 * QK);
        unsigned short* kf = (unsigned short*)d_out;
        unsigned short* vf = (unsigned short*)d_out + (size_t)TT * EE;

        gemm_kvr<<<dim3(64, 8, 3), 256, 0, stream>>>(x, sx, tmk, tmv, tmr,
                                                     Wkt, Wvt, Wrt, kf, vf, ry);
        wkv_pass_a<<<(NCHUNK * EE) / 256, 256, 0, stream>>>(kf, vf, td, Sa, Sb, Sp);
        wkv_pass_b<<<4, 256, 0, stream>>>(aa, bb, pp, td, x, Sa, Sb, Sp, ina, inb, inp,
                                          out + (size_t)TT * EE);
        wkv_pass_c<<<(NCHUNK * EE) / 256, 256, 0, stream>>>(kf, vf, tf, td, ina, inb, inp, ry);
        gemm_wo<<<dim3(64, 8), 256, 0, stream>>>(ry, Wot, x, out);
    }
}

// Round 5
// 287.340 us; speedup vs baseline: 1.2826x; 1.0015x over previous
//
#include <hip/hip_runtime.h>
#include <cstdint>
#include <cstddef>

typedef __bf16 bf16x8 __attribute__((ext_vector_type(8)));
typedef float  f32x4  __attribute__((ext_vector_type(4)));

#define TT 8192
#define EE 1024
#define NCHUNK 128
#define CLEN 64    // TT / NCHUNK
#define LDSK 40    // small-path padded LDS stride (shorts)

__device__ __forceinline__ unsigned short f2bf(float f) {
    union { float f; unsigned int u; } v; v.f = f;
    unsigned int r = v.u + 0x7FFFu + ((v.u >> 16) & 1u);
    return (unsigned short)(r >> 16);
}
__device__ __forceinline__ float b2f(unsigned int h) {
    union { unsigned int u; float f; } v; v.u = h << 16; return v.f;
}
__device__ __forceinline__ void gload_lds16(const void* g, void* l) {
    __builtin_amdgcn_global_load_lds((__attribute__((address_space(1))) void*)g,
                                     (__attribute__((address_space(3))) void*)l, 16, 0, 0);
}

// ---------------------------------------------------------------------------
// Standalone W transpose (small path). grid (32,32,4), block (32,8).
// ---------------------------------------------------------------------------
__global__ void wt_kernel(const float* __restrict__ Wk, const float* __restrict__ Wv,
                          const float* __restrict__ Wr, const float* __restrict__ Wo,
                          unsigned short* __restrict__ Tk, unsigned short* __restrict__ Tv,
                          unsigned short* __restrict__ Tr, unsigned short* __restrict__ To) {
    __shared__ float tile[32][33];
    const float* W; unsigned short* D;
    switch (blockIdx.z) {
        case 0:  W = Wk; D = Tk; break;
        case 1:  W = Wv; D = Tv; break;
        case 2:  W = Wr; D = Tr; break;
        default: W = Wo; D = To; break;
    }
    const int bx = blockIdx.x * 32, by = blockIdx.y * 32;
    const int tx = threadIdx.x, ty = threadIdx.y;
#pragma unroll
    for (int r = 0; r < 4; ++r)
        tile[ty + 8 * r][tx] = W[(size_t)(by + ty + 8 * r) * EE + bx + tx];
    __syncthreads();
#pragma unroll
    for (int r = 0; r < 4; ++r)
        D[(size_t)(bx + ty + 8 * r) * EE + by + tx] = f2bf(tile[tx][ty + 8 * r]);
}

// ---------------------------------------------------------------------------
// Fused prep: blocks [0,4096) do the 4 W transposes; blocks [4096,12288)
// do the token-shift mix -> bf16 kx/vx/rx.  1D grid 12288, block 256.
// ---------------------------------------------------------------------------
__global__ void prep_kernel(const float* __restrict__ Wk, const float* __restrict__ Wv,
                            const float* __restrict__ Wr, const float* __restrict__ Wo,
                            unsigned short* __restrict__ Tk, unsigned short* __restrict__ Tv,
                            unsigned short* __restrict__ Tr, unsigned short* __restrict__ To,
                            const float* __restrict__ x, const float* __restrict__ sx,
                            const float* __restrict__ tmk, const float* __restrict__ tmv,
                            const float* __restrict__ tmr,
                            unsigned short* __restrict__ kxb, unsigned short* __restrict__ vxb,
                            unsigned short* __restrict__ rxb) {
    const int bid = blockIdx.x;
    if (bid < 4096) {
        __shared__ float tile[32][33];
        const int z = bid >> 10;
        const float* W; unsigned short* D;
        switch (z) {
            case 0:  W = Wk; D = Tk; break;
            case 1:  W = Wv; D = Tv; break;
            case 2:  W = Wr; D = Tr; break;
            default: W = Wo; D = To; break;
        }
        const int by = ((bid >> 5) & 31) * 32, bx = (bid & 31) * 32;
        const int tx = threadIdx.x & 31, ty = threadIdx.x >> 5;   // 32 x 8
#pragma unroll
        for (int r = 0; r < 4; ++r)
            tile[ty + 8 * r][tx] = W[(size_t)(by + ty + 8 * r) * EE + bx + tx];
        __syncthreads();
#pragma unroll
        for (int r = 0; r < 4; ++r)
            D[(size_t)(bx + ty + 8 * r) * EE + by + tx] = f2bf(tile[tx][ty + 8 * r]);
    } else {
        const int gid  = (bid - 4096) * 256 + threadIdx.x;
        const int base = gid * 4;
        const int t = base >> 10;
        const int e = base & (EE - 1);
        float4 xv = *(const float4*)(x + base);
        float4 pv = (t > 0) ? *(const float4*)(x + base - EE) : *(const float4*)(sx + e);
        float4 mk = *(const float4*)(tmk + e);
        float4 mv = *(const float4*)(tmv + e);
        float4 mr = *(const float4*)(tmr + e);
        ushort4 ko, vo, ro;
        ko.x = f2bf(fmaf(mk.x, xv.x - pv.x, pv.x));
        ko.y = f2bf(fmaf(mk.y, xv.y - pv.y, pv.y));
        ko.z = f2bf(fmaf(mk.z, xv.z - pv.z, pv.z));
        ko.w = f2bf(fmaf(mk.w, xv.w - pv.w, pv.w));
        vo.x = f2bf(fmaf(mv.x, xv.x - pv.x, pv.x));
        vo.y = f2bf(fmaf(mv.y, xv.y - pv.y, pv.y));
        vo.z = f2bf(fmaf(mv.z, xv.z - pv.z, pv.z));
        vo.w = f2bf(fmaf(mv.w, xv.w - pv.w, pv.w));
        ro.x = f2bf(fmaf(mr.x, xv.x - pv.x, pv.x));
        ro.y = f2bf(fmaf(mr.y, xv.y - pv.y, pv.y));
        ro.z = f2bf(fmaf(mr.z, xv.z - pv.z, pv.z));
        ro.w = f2bf(fmaf(mr.w, xv.w - pv.w, pv.w));
        *(ushort4*)(kxb + base) = ko;
        *(ushort4*)(vxb + base) = vo;
        *(ushort4*)(rxb + base) = ro;
    }
}

// ---------------------------------------------------------------------------
// 256x128-tile bf16 GEMM, 3 operand sets via blockIdx.z (z==2 -> sigmoid).
// C bf16 [M,N] = A bf16 [M,K] @ Bt bf16 [N,K]^T.  BK=32, 256 threads.
// Wave layout: 2x2 waves, each wave 128x64 (8x4 fragments, 32 MFMA/K-step).
// grid (32, 8, 3).
// ---------------------------------------------------------------------------
__global__ __launch_bounds__(256, 2) void gemm_kvr3(
        const unsigned short* __restrict__ kxb, const unsigned short* __restrict__ vxb,
        const unsigned short* __restrict__ rxb,
        const unsigned short* __restrict__ Wkt, const unsigned short* __restrict__ Wvt,
        const unsigned short* __restrict__ Wrt,
        unsigned short* __restrict__ kf, unsigned short* __restrict__ vf,
        unsigned short* __restrict__ ry) {
    __shared__ __align__(16) unsigned short As[256 * 32];   // 16 KB
    __shared__ __align__(16) unsigned short Bs[128 * 32];   // 8 KB
    const int z = blockIdx.z;
    const unsigned short* A  = (z == 0) ? kxb : (z == 1) ? vxb : rxb;
    const unsigned short* Bt = (z == 0) ? Wkt : (z == 1) ? Wvt : Wrt;
    unsigned short* C        = (z == 0) ? kf  : (z == 1) ? vf  : ry;

    const int tid  = threadIdx.x;
    const int wave = tid >> 6, lane = tid & 63;
    const int wm = (wave >> 1) * 128, wn = (wave & 1) * 64;
    const int l15 = lane & 15, lq = lane >> 4;
    const int lrow = lane >> 2, lcol = (lane & 3) * 8;
    const int bm = blockIdx.x * 256, bn = blockIdx.y * 128;

    f32x4 acc[8][4] = {};

    for (int kt = 0; kt < 1024; kt += 32) {
        __syncthreads();
#pragma unroll
        for (int p = 0; p < 4; ++p) {
            const int r0 = p * 64 + wave * 16;
            gload_lds16(A + (size_t)(bm + r0 + lrow) * 1024 + kt + lcol, &As[r0 * 32]);
        }
#pragma unroll
        for (int p = 0; p < 2; ++p) {
            const int r0 = p * 64 + wave * 16;
            gload_lds16(Bt + (size_t)(bn + r0 + lrow) * 1024 + kt + lcol, &Bs[r0 * 32]);
        }
        __syncthreads();
        bf16x8 af[8], bfr[4];
#pragma unroll
        for (int i = 0; i < 8; ++i)
            af[i] = *(const bf16x8*)(&As[(wm + i * 16 + l15) * 32 + lq * 8]);
#pragma unroll
        for (int j = 0; j < 4; ++j)
            bfr[j] = *(const bf16x8*)(&Bs[(wn + j * 16 + l15) * 32 + lq * 8]);
#pragma unroll
        for (int i = 0; i < 8; ++i)
#pragma unroll
            for (int j = 0; j < 4; ++j)
                acc[i][j] = __builtin_amdgcn_mfma_f32_16x16x32_bf16(af[i], bfr[j], acc[i][j], 0, 0, 0);
    }

    const bool sig = (z == 2);
#pragma unroll
    for (int i = 0; i < 8; ++i)
#pragma unroll
        for (int j = 0; j < 4; ++j) {
            const int col = bn + wn + j * 16 + l15;
#pragma unroll
            for (int r = 0; r < 4; ++r) {
                const int row = bm + wm + i * 16 + lq * 4 + r;
                float val = acc[i][j][r];
                if (sig) val = 1.f / (1.f + __expf(-val));
                C[(size_t)row * 1024 + col] = f2bf(val);
            }
        }
}

// ---------------------------------------------------------------------------
// 256x128-tile Wo GEMM: C f32 = A bf16 @ Bt^T + Res.  grid (32, 8).
// ---------------------------------------------------------------------------
__global__ __launch_bounds__(256, 2) void gemm_wo_big(const unsigned short* __restrict__ A,
                                                      const unsigned short* __restrict__ Bt,
                                                      const float* __restrict__ Res,
                                                      float* __restrict__ C) {
    __shared__ __align__(16) unsigned short As[256 * 32];
    __shared__ __align__(16) unsigned short Bs[128 * 32];
    const int tid  = threadIdx.x;
    const int wave = tid >> 6, lane = tid & 63;
    const int wm = (wave >> 1) * 128, wn = (wave & 1) * 64;
    const int l15 = lane & 15, lq = lane >> 4;
    const int lrow = lane >> 2, lcol = (lane & 3) * 8;
    const int bm = blockIdx.x * 256, bn = blockIdx.y * 128;

    f32x4 acc[8][4] = {};

    for (int kt = 0; kt < 1024; kt += 32) {
        __syncthreads();
#pragma unroll
        for (int p = 0; p < 4; ++p) {
            const int r0 = p * 64 + wave * 16;
            gload_lds16(A + (size_t)(bm + r0 + lrow) * 1024 + kt + lcol, &As[r0 * 32]);
        }
#pragma unroll
        for (int p = 0; p < 2; ++p) {
            const int r0 = p * 64 + wave * 16;
            gload_lds16(Bt + (size_t)(bn + r0 + lrow) * 1024 + kt + lcol, &Bs[r0 * 32]);
        }
        __syncthreads();
        bf16x8 af[8], bfr[4];
#pragma unroll
        for (int i = 0; i < 8; ++i)
            af[i] = *(const bf16x8*)(&As[(wm + i * 16 + l15) * 32 + lq * 8]);
#pragma unroll
        for (int j = 0; j < 4; ++j)
            bfr[j] = *(const bf16x8*)(&Bs[(wn + j * 16 + l15) * 32 + lq * 8]);
#pragma unroll
        for (int i = 0; i < 8; ++i)
#pragma unroll
            for (int j = 0; j < 4; ++j)
                acc[i][j] = __builtin_amdgcn_mfma_f32_16x16x32_bf16(af[i], bfr[j], acc[i][j], 0, 0, 0);
    }

#pragma unroll
    for (int i = 0; i < 8; ++i)
#pragma unroll
        for (int j = 0; j < 4; ++j) {
            const int col = bn + wn + j * 16 + l15;
#pragma unroll
            for (int r = 0; r < 4; ++r) {
                const int row = bm + wm + i * 16 + lq * 4 + r;
                const size_t idx = (size_t)row * 1024 + col;
                C[idx] = acc[i][j][r] + Res[idx];
            }
        }
}

// ---------------------------------------------------------------------------
// MID path (59<=ws<75): m97-structure 128x128 GEMM, two operand sets via z.
// ---------------------------------------------------------------------------
__global__ __launch_bounds__(256) void gemm_bf(
        const unsigned short* __restrict__ A0, const unsigned short* __restrict__ B0,
        unsigned short* __restrict__ C0, const int sig0,
        const unsigned short* __restrict__ A1, const unsigned short* __restrict__ B1,
        unsigned short* __restrict__ C1, const int sig1) {
    __shared__ __align__(16) unsigned short As[128 * 32];
    __shared__ __align__(16) unsigned short Bs[128 * 32];
    const int z = blockIdx.z;
    const unsigned short* A  = z ? A1 : A0;
    const unsigned short* Bt = z ? B1 : B0;
    unsigned short* C        = z ? C1 : C0;
    const int sig            = z ? sig1 : sig0;

    const int tid  = threadIdx.x;
    const int wave = tid >> 6, lane = tid & 63;
    const int wm = (wave >> 1) * 64, wn = (wave & 1) * 64;
    const int l15 = lane & 15, lq = lane >> 4;
    const int lrow = lane >> 2, lcol = (lane & 3) * 8;
    const int bm = blockIdx.x * 128, bn = blockIdx.y * 128;

    f32x4 acc[4][4] = {};

    for (int kt = 0; kt < 1024; kt += 32) {
        __syncthreads();
#pragma unroll
        for (int p = 0; p < 2; ++p) {
            const int r0 = p * 64 + wave * 16;
            gload_lds16(A  + (size_t)(bm + r0 + lrow) * 1024 + kt + lcol, &As[r0 * 32]);
            gload_lds16(Bt + (size_t)(bn + r0 + lrow) * 1024 + kt + lcol, &Bs[r0 * 32]);
        }
        __syncthreads();
        bf16x8 af[4], bfr[4];
#pragma unroll
        for (int i = 0; i < 4; ++i) {
            af[i]  = *(const bf16x8*)(&As[(wm + i * 16 + l15) * 32 + lq * 8]);
            bfr[i] = *(const bf16x8*)(&Bs[(wn + i * 16 + l15) * 32 + lq * 8]);
        }
#pragma unroll
        for (int i = 0; i < 4; ++i)
#pragma unroll
            for (int j = 0; j < 4; ++j)
                acc[i][j] = __builtin_amdgcn_mfma_f32_16x16x32_bf16(af[i], bfr[j], acc[i][j], 0, 0, 0);
    }

#pragma unroll
    for (int i = 0; i < 4; ++i)
#pragma unroll
        for (int j = 0; j < 4; ++j) {
            const int col = bn + wn + j * 16 + l15;
#pragma unroll
            for (int r = 0; r < 4; ++r) {
                const int row = bm + wm + i * 16 + lq * 4 + r;
                float val = acc[i][j][r];
                if (sig) val = 1.f / (1.f + __expf(-val));
                C[(size_t)row * 1024 + col] = f2bf(val);
            }
        }
}

// ---------------------------------------------------------------------------
// SMALL path (<59 MB): fused-mix k/v/r GEMM (round-3 structure).
// ---------------------------------------------------------------------------
__global__ __launch_bounds__(256, 4) void gemm_kvr(
        const float* __restrict__ X, const float* __restrict__ SX,
        const float* __restrict__ tmk, const float* __restrict__ tmv,
        const float* __restrict__ tmr,
        const unsigned short* __restrict__ Wkt, const unsigned short* __restrict__ Wvt,
        const unsigned short* __restrict__ Wrt,
        unsigned short* __restrict__ outK, unsigned short* __restrict__ outV,
        unsigned short* __restrict__ outR) {
    __shared__ __align__(16) unsigned short As[128 * LDSK];
    __shared__ __align__(16) unsigned short Bs[128 * LDSK];
    const int z = blockIdx.z;
    const float* TM = (z == 0) ? tmk : (z == 1) ? tmv : tmr;
    const unsigned short* Bt = (z == 0) ? Wkt : (z == 1) ? Wvt : Wrt;
    unsigned short* Cout = (z == 0) ? outK : (z == 1) ? outV : outR;

    const int tid  = threadIdx.x;
    const int wave = tid >> 6, lane = tid & 63;
    const int wm = (wave >> 1) * 64, wn = (wave & 1) * 64;
    const int l15 = lane & 15, lq = lane >> 4;
    const int bm = blockIdx.x * 128, bn = blockIdx.y * 128;

    f32x4 acc[4][4] = {};

    for (int kt = 0; kt < 1024; kt += 32) {
        __syncthreads();
#pragma unroll
        for (int p = 0; p < 2; ++p) {
            const int li  = p * 256 + tid;
            const int row = li >> 2, q = li & 3;
            const int e0  = kt + q * 8;
            {
                const int t = bm + row;
                const float* xr = X + (size_t)t * EE + e0;
                const float* pr = (t > 0) ? (X + (size_t)(t - 1) * EE + e0) : (SX + e0);
                float4 xa = *(const float4*)xr, xb = *(const float4*)(xr + 4);
                float4 pa = *(const float4*)pr, pb = *(const float4*)(pr + 4);
                float4 ma = *(const float4*)(TM + e0), mb = *(const float4*)(TM + e0 + 4);
                ushort4 lo, hi;
                lo.x = f2bf(fmaf(ma.x, xa.x - pa.x, pa.x));
                lo.y = f2bf(fmaf(ma.y, xa.y - pa.y, pa.y));
                lo.z = f2bf(fmaf(ma.z, xa.z - pa.z, pa.z));
                lo.w = f2bf(fmaf(ma.w, xa.w - pa.w, pa.w));
                hi.x = f2bf(fmaf(mb.x, xb.x - pb.x, pb.x));
                hi.y = f2bf(fmaf(mb.y, xb.y - pb.y, pb.y));
                hi.z = f2bf(fmaf(mb.z, xb.z - pb.z, pb.z));
                hi.w = f2bf(fmaf(mb.w, xb.w - pb.w, pb.w));
                *(ushort4*)(&As[row * LDSK + q * 8])     = lo;
                *(ushort4*)(&As[row * LDSK + q * 8 + 4]) = hi;
            }
            *(uint4*)(&Bs[row * LDSK + q * 8]) =
                *(const uint4*)(Bt + (size_t)(bn + row) * 1024 + e0);
        }
        __syncthreads();
        bf16x8 af[4], bfr[4];
#pragma unroll
        for (int i = 0; i < 4; ++i) {
            af[i]  = *(const bf16x8*)(&As[(wm + i * 16 + l15) * LDSK + lq * 8]);
            bfr[i] = *(const bf16x8*)(&Bs[(wn + i * 16 + l15) * LDSK + lq * 8]);
        }
#pragma unroll
        for (int i = 0; i < 4; ++i)
#pragma unroll
            for (int j = 0; j < 4; ++j)
                acc[i][j] = __builtin_amdgcn_mfma_f32_16x16x32_bf16(af[i], bfr[j], acc[i][j], 0, 0, 0);
    }

    const bool sig = (z == 2);
#pragma unroll
    for (int i = 0; i < 4; ++i)
#pragma unroll
        for (int j = 0; j < 4; ++j) {
            const int col = bn + wn + j * 16 + l15;
#pragma unroll
            for (int r = 0; r < 4; ++r) {
                const int row = bm + wm + i * 16 + lq * 4 + r;
                float val = acc[i][j][r];
                if (sig) val = 1.f / (1.f + __expf(-val));
                Cout[(size_t)row * 1024 + col] = f2bf(val);
            }
        }
}

// ---------------------------------------------------------------------------
// WKV pass A: per (chunk, channel) stabilized local summary.  grid 512 x 256
// ---------------------------------------------------------------------------
__global__ void wkv_pass_a(const unsigned short* __restrict__ k,
                           const unsigned short* __restrict__ v,
                           const float* __restrict__ td,
                           float* __restrict__ Sa, float* __restrict__ Sb, float* __restrict__ Sp) {
    const int gid = blockIdx.x * 256 + threadIdx.x;
    const int c = gid >> 10, e = gid & (EE - 1);
    const float w = -__expf(td[e]);
    float sa = 0.f, sb = 0.f, sp = -1e30f;
    const size_t base = (size_t)c * CLEN * EE + e;
    for (int i = 0; i < CLEN; ++i) {
        const size_t idx = base + (size_t)i * EE;
        const float kk = b2f(k[idx]), vv = b2f(v[idx]);
        const float q  = fmaf(w, (float)(CLEN - 1 - i), kk);
        const float p2 = fmaxf(sp, q);
        const float e1 = __expf(sp - p2), e2 = __expf(q - p2);
        sa = fmaf(e1, sa, e2 * vv);
        sb = fmaf(e1, sb, e2);
        sp = p2;
    }
    Sa[gid] = sa; Sb[gid] = sb; Sp[gid] = sp;
}

// ---------------------------------------------------------------------------
// WKV pass B: sequential chunk-scan per channel + final-state outputs.
// grid 4 x 256
// ---------------------------------------------------------------------------
__global__ void wkv_pass_b(const float* __restrict__ aa, const float* __restrict__ bb,
                           const float* __restrict__ pp, const float* __restrict__ td,
                           const float* __restrict__ x,
                           const float* __restrict__ Sa, const float* __restrict__ Sb,
                           const float* __restrict__ Sp,
                           float* __restrict__ ina, float* __restrict__ inb,
                           float* __restrict__ inp, float* __restrict__ outTail) {
    const int e = blockIdx.x * 256 + threadIdx.x;
    const float w  = -__expf(td[e]);
    const float wL = w * (float)CLEN;
    float a = aa[e], b = bb[e], p = pp[e];
    for (int c = 0; c < NCHUNK; ++c) {
        const int idx = c * EE + e;
        ina[idx] = a; inb[idx] = b; inp[idx] = p;
        const float sa = Sa[idx], sb = Sb[idx], sp = Sp[idx];
        const float pw = p + wL;
        const float p2 = fmaxf(pw, sp);
        const float e1 = __expf(pw - p2), e2 = __expf(sp - p2);
        a = fmaf(e1, a, e2 * sa);
        b = fmaf(e1, b, e2 * sb);
        p = p2;
    }
    outTail[e]          = x[(size_t)(TT - 1) * EE + e];
    outTail[EE + e]     = a;
    outTail[2 * EE + e] = b;
    outTail[3 * EE + e] = p;
}

// ---------------------------------------------------------------------------
// WKV pass C: replay chunks; ry = sigmoid(r) in, y = sigmoid(r)*wkv out.
// grid 512 x 256
// ---------------------------------------------------------------------------
__global__ void wkv_pass_c(const unsigned short* __restrict__ k,
                           const unsigned short* __restrict__ v,
                           const float* __restrict__ tf, const float* __restrict__ td,
                           const float* __restrict__ ina, const float* __restrict__ inb,
                           const float* __restrict__ inp,
                           unsigned short* ry) {
    const int gid = blockIdx.x * 256 + threadIdx.x;
    const int c = gid >> 10, e = gid & (EE - 1);
    const float w = -__expf(td[e]);
    const float u = tf[e];
    float a = ina[gid], b = inb[gid], p = inp[gid];
    const size_t base = (size_t)c * CLEN * EE + e;
    for (int i = 0; i < CLEN; ++i) {
        const size_t idx = base + (size_t)i * EE;
        const float kk = b2f(k[idx]), vv = b2f(v[idx]);
        const float rr = b2f(ry[idx]);
        const float ww = u + kk;
        const float pq = fmaxf(p, ww);
        const float e1 = __expf(p - pq), e2 = __expf(ww - pq);
        const float wkv = fmaf(e1, a, e2 * vv) / fmaf(e1, b, e2);
        ry[idx] = f2bf(rr * wkv);
        const float ww2 = w + p;
        const float p2  = fmaxf(ww2, kk);
        const float e1b = __expf(ww2 - p2), e2b = __expf(kk - p2);
        a = fmaf(e1b, a, e2b * vv);
        b = fmaf(e1b, b, e2b);
        p = p2;
    }
}

// ---------------------------------------------------------------------------
extern "C" void kernel_launch(void* const* d_in, const int* in_sizes, int n_in,
                              void* d_out, int out_size, void* d_ws, size_t ws_size,
                              hipStream_t stream) {
    const float* x   = (const float*)d_in[0];
    const float* sx  = (const float*)d_in[1];
    const float* aa  = (const float*)d_in[2];
    const float* bb  = (const float*)d_in[3];
    const float* pp  = (const float*)d_in[4];
    const float* tf  = (const float*)d_in[5];
    const float* td  = (const float*)d_in[6];
    const float* tmk = (const float*)d_in[7];
    const float* tmv = (const float*)d_in[8];
    const float* tmr = (const float*)d_in[9];
    const float* Wk  = (const float*)d_in[10];
    const float* Wv  = (const float*)d_in[11];
    const float* Wr  = (const float*)d_in[12];
    const float* Wo  = (const float*)d_in[13];
    float* out = (float*)d_out;

    char* ws = (char*)d_ws;
    const size_t MB = 1ull << 20;
    const size_t QK = (size_t)NCHUNK * EE * sizeof(float);  // 512 KB

    unsigned short* Wkt = (unsigned short*)(ws + 0 * MB);   // 2 MB each
    unsigned short* Wvt = (unsigned short*)(ws + 2 * MB);
    unsigned short* Wrt = (unsigned short*)(ws + 4 * MB);
    unsigned short* Wot = (unsigned short*)(ws + 6 * MB);

    if (ws_size >= 75 * MB) {
        // ws: [0:8] Wt | [8:24] rxb | [24:40] kf | [40:56] ry | [56:72] vf | [72:75] scan
        unsigned short* rxb = (unsigned short*)(ws + 8 * MB);
        unsigned short* kf  = (unsigned short*)(ws + 24 * MB);
        unsigned short* ry  = (unsigned short*)(ws + 40 * MB);
        unsigned short* vf  = (unsigned short*)(ws + 56 * MB);
        char* scan = ws + 72 * MB;
        float* Sa  = (float*)(scan);
        float* Sb  = (float*)(scan + QK);
        float* Sp  = (float*)(scan + 2 * QK);
        float* ina = (float*)(scan + 3 * QK);
        float* inb = (float*)(scan + 4 * QK);
        float* inp = (float*)(scan + 5 * QK);
        unsigned short* kxb = (unsigned short*)d_out;                   // d_out scratch
        unsigned short* vxb = (unsigned short*)d_out + (size_t)TT * EE;

        prep_kernel<<<12288, 256, 0, stream>>>(Wk, Wv, Wr, Wo, Wkt, Wvt, Wrt, Wot,
                                               x, sx, tmk, tmv, tmr, kxb, vxb, rxb);
        gemm_kvr3<<<dim3(32, 8, 3), 256, 0, stream>>>(kxb, vxb, rxb, Wkt, Wvt, Wrt, kf, vf, ry);
        wkv_pass_a<<<(NCHUNK * EE) / 256, 256, 0, stream>>>(kf, vf, td, Sa, Sb, Sp);
        wkv_pass_b<<<4, 256, 0, stream>>>(aa, bb, pp, td, x, Sa, Sb, Sp, ina, inb, inp,
                                          out + (size_t)TT * EE);
        wkv_pass_c<<<(NCHUNK * EE) / 256, 256, 0, stream>>>(kf, vf, tf, td, ina, inb, inp, ry);
        gemm_wo_big<<<dim3(32, 8), 256, 0, stream>>>(ry, Wot, x, out);
    } else if (ws_size >= 59 * MB) {
        // round-4 proven path: [8:24] rxb | [24:40] kf | [40:56] ry | [56:59] scan
        unsigned short* rxb = (unsigned short*)(ws + 8 * MB);
        unsigned short* kf  = (unsigned short*)(ws + 24 * MB);
        unsigned short* ry  = (unsigned short*)(ws + 40 * MB);
        char* scan = ws + 56 * MB;
        float* Sa  = (float*)(scan);
        float* Sb  = (float*)(scan + QK);
        float* Sp  = (float*)(scan + 2 * QK);
        float* ina = (float*)(scan + 3 * QK);
        float* inb = (float*)(scan + 4 * QK);
        float* inp = (float*)(scan + 5 * QK);
        unsigned short* kxb = (unsigned short*)d_out;
        unsigned short* vxb = (unsigned short*)d_out + (size_t)TT * EE;
        unsigned short* vf  = kxb;   // overlays kxb after it is consumed

        prep_kernel<<<12288, 256, 0, stream>>>(Wk, Wv, Wr, Wo, Wkt, Wvt, Wrt, Wot,
                                               x, sx, tmk, tmv, tmr, kxb, vxb, rxb);
        gemm_bf<<<dim3(64, 8, 2), 256, 0, stream>>>(kxb, Wkt, kf, 0, rxb, Wrt, ry, 1);
        gemm_bf<<<dim3(64, 8, 1), 256, 0, stream>>>(vxb, Wvt, vf, 0, nullptr, nullptr, nullptr, 0);
        wkv_pass_a<<<(NCHUNK * EE) / 256, 256, 0, stream>>>(kf, vf, td, Sa, Sb, Sp);
        wkv_pass_b<<<4, 256, 0, stream>>>(aa, bb, pp, td, x, Sa, Sb, Sp, ina, inb, inp,
                                          out + (size_t)TT * EE);
        wkv_pass_c<<<(NCHUNK * EE) / 256, 256, 0, stream>>>(kf, vf, tf, td, ina, inb, inp, ry);
        gemm_wo_big<<<dim3(32, 8), 256, 0, stream>>>(ry, Wot, x, out);
    } else {
        // 27 MB proven fallback
        unsigned short* ry = (unsigned short*)(ws + 8 * MB);
        char* scan = ws + 24 * MB;
        float* Sa  = (float*)(scan);
        float* Sb  = (float*)(scan + QK);
        float* Sp  = (float*)(scan + 2 * QK);
        float* ina = (float*)(scan + 3 * QK);
        float* inb = (float*)(scan + 4 * QK);
        float* inp = (float*)(scan + 5 * QK);
        unsigned short* kf = (unsigned short*)d_out;
        unsigned short* vf = (unsigned short*)d_out + (size_t)TT * EE;

        wt_kernel<<<dim3(32, 32, 4), dim3(32, 8), 0, stream>>>(Wk, Wv, Wr, Wo, Wkt, Wvt, Wrt, Wot);
        gemm_kvr<<<dim3(64, 8, 3), 256, 0, stream>>>(x, sx, tmk, tmv, tmr,
                                                     Wkt, Wvt, Wrt, kf, vf, ry);
        wkv_pass_a<<<(NCHUNK * EE) / 256, 256, 0, stream>>>(kf, vf, td, Sa, Sb, Sp);
        wkv_pass_b<<<4, 256, 0, stream>>>(aa, bb, pp, td, x, Sa, Sb, Sp, ina, inb, inp,
                                          out + (size_t)TT * EE);
        wkv_pass_c<<<(NCHUNK * EE) / 256, 256, 0, stream>>>(kf, vf, tf, td, ina, inb, inp, ry);
        gemm_wo_big<<<dim3(32, 8), 256, 0, stream>>>(ry, Wot, x, out);
    }
}

// Round 6
// 271.628 us; speedup vs baseline: 1.3568x; 1.0578x over previous
//
#include <hip/hip_runtime.h>
#include <cstdint>
#include <cstddef>

typedef __bf16 bf16x8 __attribute__((ext_vector_type(8)));
typedef float  f32x4  __attribute__((ext_vector_type(4)));

#define TT 8192
#define EE 1024
#define NCHUNK 128
#define CLEN 64    // TT / NCHUNK
#define LDSK 40    // small-path padded LDS stride (shorts)

__device__ __forceinline__ unsigned short f2bf(float f) {
    union { float f; unsigned int u; } v; v.f = f;
    unsigned int r = v.u + 0x7FFFu + ((v.u >> 16) & 1u);
    return (unsigned short)(r >> 16);
}
__device__ __forceinline__ float b2f(unsigned int h) {
    union { unsigned int u; float f; } v; v.u = h << 16; return v.f;
}
__device__ __forceinline__ void gload_lds16(const void* g, void* l) {
    __builtin_amdgcn_global_load_lds((__attribute__((address_space(1))) void*)g,
                                     (__attribute__((address_space(3))) void*)l, 16, 0, 0);
}

// ---------------------------------------------------------------------------
// Standalone W transpose (small path). grid (32,32,4), block (32,8).
// ---------------------------------------------------------------------------
__global__ void wt_kernel(const float* __restrict__ Wk, const float* __restrict__ Wv,
                          const float* __restrict__ Wr, const float* __restrict__ Wo,
                          unsigned short* __restrict__ Tk, unsigned short* __restrict__ Tv,
                          unsigned short* __restrict__ Tr, unsigned short* __restrict__ To) {
    __shared__ float tile[32][33];
    const float* W; unsigned short* D;
    switch (blockIdx.z) {
        case 0:  W = Wk; D = Tk; break;
        case 1:  W = Wv; D = Tv; break;
        case 2:  W = Wr; D = Tr; break;
        default: W = Wo; D = To; break;
    }
    const int bx = blockIdx.x * 32, by = blockIdx.y * 32;
    const int tx = threadIdx.x, ty = threadIdx.y;
#pragma unroll
    for (int r = 0; r < 4; ++r)
        tile[ty + 8 * r][tx] = W[(size_t)(by + ty + 8 * r) * EE + bx + tx];
    __syncthreads();
#pragma unroll
    for (int r = 0; r < 4; ++r)
        D[(size_t)(bx + ty + 8 * r) * EE + by + tx] = f2bf(tile[tx][ty + 8 * r]);
}

// ---------------------------------------------------------------------------
// Fused prep: blocks [0,4096) transpose the 4 Ws; blocks [4096,12288) do the
// token-shift mix -> bf16 kx/vx/rx.  1D grid 12288, block 256.
// ---------------------------------------------------------------------------
__global__ void prep_kernel(const float* __restrict__ Wk, const float* __restrict__ Wv,
                            const float* __restrict__ Wr, const float* __restrict__ Wo,
                            unsigned short* __restrict__ Tk, unsigned short* __restrict__ Tv,
                            unsigned short* __restrict__ Tr, unsigned short* __restrict__ To,
                            const float* __restrict__ x, const float* __restrict__ sx,
                            const float* __restrict__ tmk, const float* __restrict__ tmv,
                            const float* __restrict__ tmr,
                            unsigned short* __restrict__ kxb, unsigned short* __restrict__ vxb,
                            unsigned short* __restrict__ rxb) {
    const int bid = blockIdx.x;
    if (bid < 4096) {
        __shared__ float tile[32][33];
        const int z = bid >> 10;
        const float* W; unsigned short* D;
        switch (z) {
            case 0:  W = Wk; D = Tk; break;
            case 1:  W = Wv; D = Tv; break;
            case 2:  W = Wr; D = Tr; break;
            default: W = Wo; D = To; break;
        }
        const int by = ((bid >> 5) & 31) * 32, bx = (bid & 31) * 32;
        const int tx = threadIdx.x & 31, ty = threadIdx.x >> 5;   // 32 x 8
#pragma unroll
        for (int r = 0; r < 4; ++r)
            tile[ty + 8 * r][tx] = W[(size_t)(by + ty + 8 * r) * EE + bx + tx];
        __syncthreads();
#pragma unroll
        for (int r = 0; r < 4; ++r)
            D[(size_t)(bx + ty + 8 * r) * EE + by + tx] = f2bf(tile[tx][ty + 8 * r]);
    } else {
        const int gid  = (bid - 4096) * 256 + threadIdx.x;
        const int base = gid * 4;
        const int t = base >> 10;
        const int e = base & (EE - 1);
        float4 xv = *(const float4*)(x + base);
        float4 pv = (t > 0) ? *(const float4*)(x + base - EE) : *(const float4*)(sx + e);
        float4 mk = *(const float4*)(tmk + e);
        float4 mv = *(const float4*)(tmv + e);
        float4 mr = *(const float4*)(tmr + e);
        ushort4 ko, vo, ro;
        ko.x = f2bf(fmaf(mk.x, xv.x - pv.x, pv.x));
        ko.y = f2bf(fmaf(mk.y, xv.y - pv.y, pv.y));
        ko.z = f2bf(fmaf(mk.z, xv.z - pv.z, pv.z));
        ko.w = f2bf(fmaf(mk.w, xv.w - pv.w, pv.w));
        vo.x = f2bf(fmaf(mv.x, xv.x - pv.x, pv.x));
        vo.y = f2bf(fmaf(mv.y, xv.y - pv.y, pv.y));
        vo.z = f2bf(fmaf(mv.z, xv.z - pv.z, pv.z));
        vo.w = f2bf(fmaf(mv.w, xv.w - pv.w, pv.w));
        ro.x = f2bf(fmaf(mr.x, xv.x - pv.x, pv.x));
        ro.y = f2bf(fmaf(mr.y, xv.y - pv.y, pv.y));
        ro.z = f2bf(fmaf(mr.z, xv.z - pv.z, pv.z));
        ro.w = f2bf(fmaf(mr.w, xv.w - pv.w, pv.w));
        *(ushort4*)(kxb + base) = ko;
        *(ushort4*)(vxb + base) = vo;
        *(ushort4*)(rxb + base) = ro;
    }
}

// ---------------------------------------------------------------------------
// 256x128-tile bf16 GEMM, BK=64, 3 operand sets via blockIdx.z (z==2 -> sig).
// C bf16 [M,N] = A bf16 [M,K] @ Bt bf16 [N,K]^T.  256 threads, grid (32,8,3).
// Wave layout: 2x2 waves, each wave 128x64 (8x4 frags, 64 MFMA per K-iter).
// 16 K-iterations (half the barrier drains of BK=32).
// ---------------------------------------------------------------------------
__global__ __launch_bounds__(256, 2) void gemm_kvr3(
        const unsigned short* __restrict__ kxb, const unsigned short* __restrict__ vxb,
        const unsigned short* __restrict__ rxb,
        const unsigned short* __restrict__ Wkt, const unsigned short* __restrict__ Wvt,
        const unsigned short* __restrict__ Wrt,
        unsigned short* __restrict__ kf, unsigned short* __restrict__ vf,
        unsigned short* __restrict__ ry) {
    __shared__ __align__(16) unsigned short As[256 * 64];   // 32 KB
    __shared__ __align__(16) unsigned short Bs[128 * 64];   // 16 KB
    const int z = blockIdx.z;
    const unsigned short* A  = (z == 0) ? kxb : (z == 1) ? vxb : rxb;
    const unsigned short* Bt = (z == 0) ? Wkt : (z == 1) ? Wvt : Wrt;
    unsigned short* C        = (z == 0) ? kf  : (z == 1) ? vf  : ry;

    const int tid  = threadIdx.x;
    const int wave = tid >> 6, lane = tid & 63;
    const int wm = (wave >> 1) * 128, wn = (wave & 1) * 64;
    const int l15 = lane & 15, lq = lane >> 4;
    const int lrow = lane >> 3, lcol = (lane & 7) * 8;   // staging: 8 lanes/row
    const int bm = blockIdx.x * 256, bn = blockIdx.y * 128;

    f32x4 acc[8][4] = {};

    for (int kt = 0; kt < 1024; kt += 64) {
        __syncthreads();
#pragma unroll
        for (int p = 0; p < 8; ++p) {
            const int r0 = p * 32 + wave * 8;
            gload_lds16(A + (size_t)(bm + r0 + lrow) * 1024 + kt + lcol, &As[r0 * 64]);
        }
#pragma unroll
        for (int p = 0; p < 4; ++p) {
            const int r0 = p * 32 + wave * 8;
            gload_lds16(Bt + (size_t)(bn + r0 + lrow) * 1024 + kt + lcol, &Bs[r0 * 64]);
        }
        __syncthreads();
#pragma unroll
        for (int h = 0; h < 2; ++h) {
            bf16x8 af[8], bfr[4];
#pragma unroll
            for (int i = 0; i < 8; ++i)
                af[i] = *(const bf16x8*)(&As[(wm + i * 16 + l15) * 64 + h * 32 + lq * 8]);
#pragma unroll
            for (int j = 0; j < 4; ++j)
                bfr[j] = *(const bf16x8*)(&Bs[(wn + j * 16 + l15) * 64 + h * 32 + lq * 8]);
#pragma unroll
            for (int i = 0; i < 8; ++i)
#pragma unroll
                for (int j = 0; j < 4; ++j)
                    acc[i][j] = __builtin_amdgcn_mfma_f32_16x16x32_bf16(af[i], bfr[j], acc[i][j], 0, 0, 0);
        }
    }

    const bool sig = (z == 2);
#pragma unroll
    for (int i = 0; i < 8; ++i)
#pragma unroll
        for (int j = 0; j < 4; ++j) {
            const int col = bn + wn + j * 16 + l15;
#pragma unroll
            for (int r = 0; r < 4; ++r) {
                const int row = bm + wm + i * 16 + lq * 4 + r;
                float val = acc[i][j][r];
                if (sig) val = 1.f / (1.f + __expf(-val));
                C[(size_t)row * 1024 + col] = f2bf(val);
            }
        }
}

// ---------------------------------------------------------------------------
// Wo GEMM: 128x128 tile, BK=64.  C f32 = A bf16 @ Bt^T + Res.  grid (64,8)
// = 512 blocks (2 blocks/CU vs 1 for the 256-tile variant).
// ---------------------------------------------------------------------------
__global__ __launch_bounds__(256, 2) void gemm_wo(const unsigned short* __restrict__ A,
                                                  const unsigned short* __restrict__ Bt,
                                                  const float* __restrict__ Res,
                                                  float* __restrict__ C) {
    __shared__ __align__(16) unsigned short As[128 * 64];   // 16 KB
    __shared__ __align__(16) unsigned short Bs[128 * 64];   // 16 KB
    const int tid  = threadIdx.x;
    const int wave = tid >> 6, lane = tid & 63;
    const int wm = (wave >> 1) * 64, wn = (wave & 1) * 64;
    const int l15 = lane & 15, lq = lane >> 4;
    const int lrow = lane >> 3, lcol = (lane & 7) * 8;
    const int bm = blockIdx.x * 128, bn = blockIdx.y * 128;

    f32x4 acc[4][4] = {};

    for (int kt = 0; kt < 1024; kt += 64) {
        __syncthreads();
#pragma unroll
        for (int p = 0; p < 4; ++p) {
            const int r0 = p * 32 + wave * 8;
            gload_lds16(A  + (size_t)(bm + r0 + lrow) * 1024 + kt + lcol, &As[r0 * 64]);
            gload_lds16(Bt + (size_t)(bn + r0 + lrow) * 1024 + kt + lcol, &Bs[r0 * 64]);
        }
        __syncthreads();
#pragma unroll
        for (int h = 0; h < 2; ++h) {
            bf16x8 af[4], bfr[4];
#pragma unroll
            for (int i = 0; i < 4; ++i) {
                af[i]  = *(const bf16x8*)(&As[(wm + i * 16 + l15) * 64 + h * 32 + lq * 8]);
                bfr[i] = *(const bf16x8*)(&Bs[(wn + i * 16 + l15) * 64 + h * 32 + lq * 8]);
            }
#pragma unroll
            for (int i = 0; i < 4; ++i)
#pragma unroll
                for (int j = 0; j < 4; ++j)
                    acc[i][j] = __builtin_amdgcn_mfma_f32_16x16x32_bf16(af[i], bfr[j], acc[i][j], 0, 0, 0);
        }
    }

#pragma unroll
    for (int i = 0; i < 4; ++i)
#pragma unroll
        for (int j = 0; j < 4; ++j) {
            const int col = bn + wn + j * 16 + l15;
#pragma unroll
            for (int r = 0; r < 4; ++r) {
                const int row = bm + wm + i * 16 + lq * 4 + r;
                const size_t idx = (size_t)row * 1024 + col;
                C[idx] = acc[i][j][r] + Res[idx];
            }
        }
}

// ---------------------------------------------------------------------------
// MID path (59<=ws<75): m97-structure 128x128 BK=32 GEMM, two sets via z.
// ---------------------------------------------------------------------------
__global__ __launch_bounds__(256) void gemm_bf(
        const unsigned short* __restrict__ A0, const unsigned short* __restrict__ B0,
        unsigned short* __restrict__ C0, const int sig0,
        const unsigned short* __restrict__ A1, const unsigned short* __restrict__ B1,
        unsigned short* __restrict__ C1, const int sig1) {
    __shared__ __align__(16) unsigned short As[128 * 32];
    __shared__ __align__(16) unsigned short Bs[128 * 32];
    const int z = blockIdx.z;
    const unsigned short* A  = z ? A1 : A0;
    const unsigned short* Bt = z ? B1 : B0;
    unsigned short* C        = z ? C1 : C0;
    const int sig            = z ? sig1 : sig0;

    const int tid  = threadIdx.x;
    const int wave = tid >> 6, lane = tid & 63;
    const int wm = (wave >> 1) * 64, wn = (wave & 1) * 64;
    const int l15 = lane & 15, lq = lane >> 4;
    const int lrow = lane >> 2, lcol = (lane & 3) * 8;
    const int bm = blockIdx.x * 128, bn = blockIdx.y * 128;

    f32x4 acc[4][4] = {};

    for (int kt = 0; kt < 1024; kt += 32) {
        __syncthreads();
#pragma unroll
        for (int p = 0; p < 2; ++p) {
            const int r0 = p * 64 + wave * 16;
            gload_lds16(A  + (size_t)(bm + r0 + lrow) * 1024 + kt + lcol, &As[r0 * 32]);
            gload_lds16(Bt + (size_t)(bn + r0 + lrow) * 1024 + kt + lcol, &Bs[r0 * 32]);
        }
        __syncthreads();
        bf16x8 af[4], bfr[4];
#pragma unroll
        for (int i = 0; i < 4; ++i) {
            af[i]  = *(const bf16x8*)(&As[(wm + i * 16 + l15) * 32 + lq * 8]);
            bfr[i] = *(const bf16x8*)(&Bs[(wn + i * 16 + l15) * 32 + lq * 8]);
        }
#pragma unroll
        for (int i = 0; i < 4; ++i)
#pragma unroll
            for (int j = 0; j < 4; ++j)
                acc[i][j] = __builtin_amdgcn_mfma_f32_16x16x32_bf16(af[i], bfr[j], acc[i][j], 0, 0, 0);
    }

#pragma unroll
    for (int i = 0; i < 4; ++i)
#pragma unroll
        for (int j = 0; j < 4; ++j) {
            const int col = bn + wn + j * 16 + l15;
#pragma unroll
            for (int r = 0; r < 4; ++r) {
                const int row = bm + wm + i * 16 + lq * 4 + r;
                float val = acc[i][j][r];
                if (sig) val = 1.f / (1.f + __expf(-val));
                C[(size_t)row * 1024 + col] = f2bf(val);
            }
        }
}

// ---------------------------------------------------------------------------
// SMALL path (<59 MB): fused-mix k/v/r GEMM (round-3 structure).
// ---------------------------------------------------------------------------
__global__ __launch_bounds__(256, 4) void gemm_kvr(
        const float* __restrict__ X, const float* __restrict__ SX,
        const float* __restrict__ tmk, const float* __restrict__ tmv,
        const float* __restrict__ tmr,
        const unsigned short* __restrict__ Wkt, const unsigned short* __restrict__ Wvt,
        const unsigned short* __restrict__ Wrt,
        unsigned short* __restrict__ outK, unsigned short* __restrict__ outV,
        unsigned short* __restrict__ outR) {
    __shared__ __align__(16) unsigned short As[128 * LDSK];
    __shared__ __align__(16) unsigned short Bs[128 * LDSK];
    const int z = blockIdx.z;
    const float* TM = (z == 0) ? tmk : (z == 1) ? tmv : tmr;
    const unsigned short* Bt = (z == 0) ? Wkt : (z == 1) ? Wvt : Wrt;
    unsigned short* Cout = (z == 0) ? outK : (z == 1) ? outV : outR;

    const int tid  = threadIdx.x;
    const int wave = tid >> 6, lane = tid & 63;
    const int wm = (wave >> 1) * 64, wn = (wave & 1) * 64;
    const int l15 = lane & 15, lq = lane >> 4;
    const int bm = blockIdx.x * 128, bn = blockIdx.y * 128;

    f32x4 acc[4][4] = {};

    for (int kt = 0; kt < 1024; kt += 32) {
        __syncthreads();
#pragma unroll
        for (int p = 0; p < 2; ++p) {
            const int li  = p * 256 + tid;
            const int row = li >> 2, q = li & 3;
            const int e0  = kt + q * 8;
            {
                const int t = bm + row;
                const float* xr = X + (size_t)t * EE + e0;
                const float* pr = (t > 0) ? (X + (size_t)(t - 1) * EE + e0) : (SX + e0);
                float4 xa = *(const float4*)xr, xb = *(const float4*)(xr + 4);
                float4 pa = *(const float4*)pr, pb = *(const float4*)(pr + 4);
                float4 ma = *(const float4*)(TM + e0), mb = *(const float4*)(TM + e0 + 4);
                ushort4 lo, hi;
                lo.x = f2bf(fmaf(ma.x, xa.x - pa.x, pa.x));
                lo.y = f2bf(fmaf(ma.y, xa.y - pa.y, pa.y));
                lo.z = f2bf(fmaf(ma.z, xa.z - pa.z, pa.z));
                lo.w = f2bf(fmaf(ma.w, xa.w - pa.w, pa.w));
                hi.x = f2bf(fmaf(mb.x, xb.x - pb.x, pb.x));
                hi.y = f2bf(fmaf(mb.y, xb.y - pb.y, pb.y));
                hi.z = f2bf(fmaf(mb.z, xb.z - pb.z, pb.z));
                hi.w = f2bf(fmaf(mb.w, xb.w - pb.w, pb.w));
                *(ushort4*)(&As[row * LDSK + q * 8])     = lo;
                *(ushort4*)(&As[row * LDSK + q * 8 + 4]) = hi;
            }
            *(uint4*)(&Bs[row * LDSK + q * 8]) =
                *(const uint4*)(Bt + (size_t)(bn + row) * 1024 + e0);
        }
        __syncthreads();
        bf16x8 af[4], bfr[4];
#pragma unroll
        for (int i = 0; i < 4; ++i) {
            af[i]  = *(const bf16x8*)(&As[(wm + i * 16 + l15) * LDSK + lq * 8]);
            bfr[i] = *(const bf16x8*)(&Bs[(wn + i * 16 + l15) * LDSK + lq * 8]);
        }
#pragma unroll
        for (int i = 0; i < 4; ++i)
#pragma unroll
            for (int j = 0; j < 4; ++j)
                acc[i][j] = __builtin_amdgcn_mfma_f32_16x16x32_bf16(af[i], bfr[j], acc[i][j], 0, 0, 0);
    }

    const bool sig = (z == 2);
#pragma unroll
    for (int i = 0; i < 4; ++i)
#pragma unroll
        for (int j = 0; j < 4; ++j) {
            const int col = bn + wn + j * 16 + l15;
#pragma unroll
            for (int r = 0; r < 4; ++r) {
                const int row = bm + wm + i * 16 + lq * 4 + r;
                float val = acc[i][j][r];
                if (sig) val = 1.f / (1.f + __expf(-val));
                Cout[(size_t)row * 1024 + col] = f2bf(val);
            }
        }
}

// ---------------------------------------------------------------------------
// WKV pass A: per (chunk, channel) stabilized local summary.  grid 512 x 256
// ---------------------------------------------------------------------------
__global__ void wkv_pass_a(const unsigned short* __restrict__ k,
                           const unsigned short* __restrict__ v,
                           const float* __restrict__ td,
                           float* __restrict__ Sa, float* __restrict__ Sb, float* __restrict__ Sp) {
    const int gid = blockIdx.x * 256 + threadIdx.x;
    const int c = gid >> 10, e = gid & (EE - 1);
    const float w = -__expf(td[e]);
    float sa = 0.f, sb = 0.f, sp = -1e30f;
    const size_t base = (size_t)c * CLEN * EE + e;
    for (int i = 0; i < CLEN; ++i) {
        const size_t idx = base + (size_t)i * EE;
        const float kk = b2f(k[idx]), vv = b2f(v[idx]);
        const float q  = fmaf(w, (float)(CLEN - 1 - i), kk);
        const float p2 = fmaxf(sp, q);
        const float e1 = __expf(sp - p2), e2 = __expf(q - p2);
        sa = fmaf(e1, sa, e2 * vv);
        sb = fmaf(e1, sb, e2);
        sp = p2;
    }
    Sa[gid] = sa; Sb[gid] = sb; Sp[gid] = sp;
}

// ---------------------------------------------------------------------------
// WKV pass B: sequential chunk-scan per channel + final-state outputs.
// grid 4 x 256
// ---------------------------------------------------------------------------
__global__ void wkv_pass_b(const float* __restrict__ aa, const float* __restrict__ bb,
                           const float* __restrict__ pp, const float* __restrict__ td,
                           const float* __restrict__ x,
                           const float* __restrict__ Sa, const float* __restrict__ Sb,
                           const float* __restrict__ Sp,
                           float* __restrict__ ina, float* __restrict__ inb,
                           float* __restrict__ inp, float* __restrict__ outTail) {
    const int e = blockIdx.x * 256 + threadIdx.x;
    const float w  = -__expf(td[e]);
    const float wL = w * (float)CLEN;
    float a = aa[e], b = bb[e], p = pp[e];
    for (int c = 0; c < NCHUNK; ++c) {
        const int idx = c * EE + e;
        ina[idx] = a; inb[idx] = b; inp[idx] = p;
        const float sa = Sa[idx], sb = Sb[idx], sp = Sp[idx];
        const float pw = p + wL;
        const float p2 = fmaxf(pw, sp);
        const float e1 = __expf(pw - p2), e2 = __expf(sp - p2);
        a = fmaf(e1, a, e2 * sa);
        b = fmaf(e1, b, e2 * sb);
        p = p2;
    }
    outTail[e]          = x[(size_t)(TT - 1) * EE + e];
    outTail[EE + e]     = a;
    outTail[2 * EE + e] = b;
    outTail[3 * EE + e] = p;
}

// ---------------------------------------------------------------------------
// WKV pass C: replay chunks; ry = sigmoid(r) in, y = sigmoid(r)*wkv out.
// grid 512 x 256
// ---------------------------------------------------------------------------
__global__ void wkv_pass_c(const unsigned short* __restrict__ k,
                           const unsigned short* __restrict__ v,
                           const float* __restrict__ tf, const float* __restrict__ td,
                           const float* __restrict__ ina, const float* __restrict__ inb,
                           const float* __restrict__ inp,
                           unsigned short* ry) {
    const int gid = blockIdx.x * 256 + threadIdx.x;
    const int c = gid >> 10, e = gid & (EE - 1);
    const float w = -__expf(td[e]);
    const float u = tf[e];
    float a = ina[gid], b = inb[gid], p = inp[gid];
    const size_t base = (size_t)c * CLEN * EE + e;
    for (int i = 0; i < CLEN; ++i) {
        const size_t idx = base + (size_t)i * EE;
        const float kk = b2f(k[idx]), vv = b2f(v[idx]);
        const float rr = b2f(ry[idx]);
        const float ww = u + kk;
        const float pq = fmaxf(p, ww);
        const float e1 = __expf(p - pq), e2 = __expf(ww - pq);
        const float wkv = fmaf(e1, a, e2 * vv) / fmaf(e1, b, e2);
        ry[idx] = f2bf(rr * wkv);
        const float ww2 = w + p;
        const float p2  = fmaxf(ww2, kk);
        const float e1b = __expf(ww2 - p2), e2b = __expf(kk - p2);
        a = fmaf(e1b, a, e2b * vv);
        b = fmaf(e1b, b, e2b);
        p = p2;
    }
}

// ---------------------------------------------------------------------------
extern "C" void kernel_launch(void* const* d_in, const int* in_sizes, int n_in,
                              void* d_out, int out_size, void* d_ws, size_t ws_size,
                              hipStream_t stream) {
    const float* x   = (const float*)d_in[0];
    const float* sx  = (const float*)d_in[1];
    const float* aa  = (const float*)d_in[2];
    const float* bb  = (const float*)d_in[3];
    const float* pp  = (const float*)d_in[4];
    const float* tf  = (const float*)d_in[5];
    const float* td  = (const float*)d_in[6];
    const float* tmk = (const float*)d_in[7];
    const float* tmv = (const float*)d_in[8];
    const float* tmr = (const float*)d_in[9];
    const float* Wk  = (const float*)d_in[10];
    const float* Wv  = (const float*)d_in[11];
    const float* Wr  = (const float*)d_in[12];
    const float* Wo  = (const float*)d_in[13];
    float* out = (float*)d_out;

    char* ws = (char*)d_ws;
    const size_t MB = 1ull << 20;
    const size_t QK = (size_t)NCHUNK * EE * sizeof(float);  // 512 KB

    unsigned short* Wkt = (unsigned short*)(ws + 0 * MB);   // 2 MB each
    unsigned short* Wvt = (unsigned short*)(ws + 2 * MB);
    unsigned short* Wrt = (unsigned short*)(ws + 4 * MB);
    unsigned short* Wot = (unsigned short*)(ws + 6 * MB);

    if (ws_size >= 75 * MB) {
        // ws: [0:8] Wt | [8:24] rxb | [24:40] kf | [40:56] ry | [56:72] vf | [72:75] scan
        unsigned short* rxb = (unsigned short*)(ws + 8 * MB);
        unsigned short* kf  = (unsigned short*)(ws + 24 * MB);
        unsigned short* ry  = (unsigned short*)(ws + 40 * MB);
        unsigned short* vf  = (unsigned short*)(ws + 56 * MB);
        char* scan = ws + 72 * MB;
        float* Sa  = (float*)(scan);
        float* Sb  = (float*)(scan + QK);
        float* Sp  = (float*)(scan + 2 * QK);
        float* ina = (float*)(scan + 3 * QK);
        float* inb = (float*)(scan + 4 * QK);
        float* inp = (float*)(scan + 5 * QK);
        unsigned short* kxb = (unsigned short*)d_out;                   // d_out scratch
        unsigned short* vxb = (unsigned short*)d_out + (size_t)TT * EE;

        prep_kernel<<<12288, 256, 0, stream>>>(Wk, Wv, Wr, Wo, Wkt, Wvt, Wrt, Wot,
                                               x, sx, tmk, tmv, tmr, kxb, vxb, rxb);
        gemm_kvr3<<<dim3(32, 8, 3), 256, 0, stream>>>(kxb, vxb, rxb, Wkt, Wvt, Wrt, kf, vf, ry);
        wkv_pass_a<<<(NCHUNK * EE) / 256, 256, 0, stream>>>(kf, vf, td, Sa, Sb, Sp);
        wkv_pass_b<<<4, 256, 0, stream>>>(aa, bb, pp, td, x, Sa, Sb, Sp, ina, inb, inp,
                                          out + (size_t)TT * EE);
        wkv_pass_c<<<(NCHUNK * EE) / 256, 256, 0, stream>>>(kf, vf, tf, td, ina, inb, inp, ry);
        gemm_wo<<<dim3(64, 8), 256, 0, stream>>>(ry, Wot, x, out);
    } else if (ws_size >= 59 * MB) {
        // [8:24] rxb | [24:40] kf | [40:56] ry | [56:59] scan
        unsigned short* rxb = (unsigned short*)(ws + 8 * MB);
        unsigned short* kf  = (unsigned short*)(ws + 24 * MB);
        unsigned short* ry  = (unsigned short*)(ws + 40 * MB);
        char* scan = ws + 56 * MB;
        float* Sa  = (float*)(scan);
        float* Sb  = (float*)(scan + QK);
        float* Sp  = (float*)(scan + 2 * QK);
        float* ina = (float*)(scan + 3 * QK);
        float* inb = (float*)(scan + 4 * QK);
        float* inp = (float*)(scan + 5 * QK);
        unsigned short* kxb = (unsigned short*)d_out;
        unsigned short* vxb = (unsigned short*)d_out + (size_t)TT * EE;
        unsigned short* vf  = kxb;   // overlays kxb after it is consumed

        prep_kernel<<<12288, 256, 0, stream>>>(Wk, Wv, Wr, Wo, Wkt, Wvt, Wrt, Wot,
                                               x, sx, tmk, tmv, tmr, kxb, vxb, rxb);
        gemm_bf<<<dim3(64, 8, 2), 256, 0, stream>>>(kxb, Wkt, kf, 0, rxb, Wrt, ry, 1);
        gemm_bf<<<dim3(64, 8, 1), 256, 0, stream>>>(vxb, Wvt, vf, 0, nullptr, nullptr, nullptr, 0);
        wkv_pass_a<<<(NCHUNK * EE) / 256, 256, 0, stream>>>(kf, vf, td, Sa, Sb, Sp);
        wkv_pass_b<<<4, 256, 0, stream>>>(aa, bb, pp, td, x, Sa, Sb, Sp, ina, inb, inp,
                                          out + (size_t)TT * EE);
        wkv_pass_c<<<(NCHUNK * EE) / 256, 256, 0, stream>>>(kf, vf, tf, td, ina, inb, inp, ry);
        gemm_wo<<<dim3(64, 8), 256, 0, stream>>>(ry, Wot, x, out);
    } else {
        // 27 MB proven fallback
        unsigned short* ry = (unsigned short*)(ws + 8 * MB);
        char* scan = ws + 24 * MB;
        float* Sa  = (float*)(scan);
        float* Sb  = (float*)(scan + QK);
        float* Sp  = (float*)(scan + 2 * QK);
        float* ina = (float*)(scan + 3 * QK);
        float* inb = (float*)(scan + 4 * QK);
        float* inp = (float*)(scan + 5 * QK);
        unsigned short* kf = (unsigned short*)d_out;
        unsigned short* vf = (unsigned short*)d_out + (size_t)TT * EE;

        wt_kernel<<<dim3(32, 32, 4), dim3(32, 8), 0, stream>>>(Wk, Wv, Wr, Wo, Wkt, Wvt, Wrt, Wot);
        gemm_kvr<<<dim3(64, 8, 3), 256, 0, stream>>>(x, sx, tmk, tmv, tmr,
                                                     Wkt, Wvt, Wrt, kf, vf, ry);
        wkv_pass_a<<<(NCHUNK * EE) / 256, 256, 0, stream>>>(kf, vf, td, Sa, Sb, Sp);
        wkv_pass_b<<<4, 256, 0, stream>>>(aa, bb, pp, td, x, Sa, Sb, Sp, ina, inb, inp,
                                          out + (size_t)TT * EE);
        wkv_pass_c<<<(NCHUNK * EE) / 256, 256, 0, stream>>>(kf, vf, tf, td, ina, inb, inp, ry);
        gemm_wo<<<dim3(64, 8), 256, 0, stream>>>(ry, Wot, x, out);
    }
}